// Round 1
// baseline (190.598 us; speedup 1.0000x reference)
//
#include <hip/hip_runtime.h>
#include <math.h>

#define BATCH 4
#define SEQ   4096
#define EMB   1024
#define HD    128
#define MROWS (BATCH*SEQ)
#define SCALE  0.08838834764831844f   // 1/sqrt(128)
#define SCALEQ 0.12751742f            // (1/sqrt(128)) * log2(e)  -> exp2-domain scores
#define CHUNK 10                      // kv-tiles (of 64) per split-KV job
#define NJOBS 119                     // jobs per batch at BQ=128, CHUNK=10
#define MAXC  7                       // max chunks per q-tile = ceil(64/10)

typedef __attribute__((ext_vector_type(8))) short bf16x8;   // MFMA A/B frag (4 VGPR)
typedef __attribute__((ext_vector_type(4))) short short4v;  // 8B LDS store
typedef __attribute__((ext_vector_type(4))) float f32x4;    // MFMA C/D frag
typedef __attribute__((ext_vector_type(4))) int   i32x4;    // 16B copy

static __device__ __forceinline__ unsigned short f2bf(float f) {
    unsigned int u = __float_as_uint(f);
    u += 0x7fff + ((u >> 16) & 1);       // RNE
    return (unsigned short)(u >> 16);
}
static __device__ __forceinline__ float bf2f(unsigned short s) {
    return __uint_as_float((unsigned int)s << 16);
}

// ---------------- W transpose + bf16 (+ fold q-scale * log2e) ----------------
// grid (64, 3) x 256 thr. Block: 16 k-rows x 128 n of one matrix, via LDS transpose.
__global__ __launch_bounds__(256) void wtrans_kernel(
    const float* __restrict__ Wq, const float* __restrict__ Wk,
    const float* __restrict__ Wv, unsigned short* __restrict__ Wt)
{
    __shared__ __align__(16) unsigned short Xs[16 * 132];
    const int w  = blockIdx.y;
    const float* W = (w == 0) ? Wq : (w == 1) ? Wk : Wv;
    const float sc = (w == 0) ? SCALEQ : 1.0f;   // exp2-domain: scores carry log2(e)
    unsigned short* dst = Wt + (size_t)w * 131072;
    const int k0 = blockIdx.x * 16;
    const int t  = threadIdx.x;

#pragma unroll
    for (int i = 0; i < 2; ++i) {
        int gg = i * 256 + t;                 // 0..511
        int row = gg >> 5, c4 = gg & 31;
        float4 a = *(const float4*)&W[(size_t)(k0 + row) * HD + c4 * 4];
        short4v p;
        p[0] = (short)f2bf(a.x * sc); p[1] = (short)f2bf(a.y * sc);
        p[2] = (short)f2bf(a.z * sc); p[3] = (short)f2bf(a.w * sc);
        *(short4v*)&Xs[row * 132 + c4 * 4] = p;
    }
    __syncthreads();
    const int n = t >> 1, half = t & 1;
    i32x4 o;
#pragma unroll
    for (int e = 0; e < 4; ++e) {
        unsigned int lo = Xs[(half * 8 + e * 2    ) * 132 + n];
        unsigned int hi = Xs[(half * 8 + e * 2 + 1) * 132 + n];
        o[e] = (int)(lo | (hi << 16));
    }
    *(i32x4*)&dst[(size_t)n * 1024 + k0 + half * 8] = o;
}

// ---------------- Fused QKV: read x once; W frags direct from L2; x dbuf ----------------
// grid 512 x 512 thr (8 waves). Wave ng owns n-tiles 3ng..3ng+2 (48 W rows) and both
// 16-row m-tiles. B-fragments are loaded DIRECTLY from Wt (L2-resident, 786 KB) —
// fragment layout == row-major 16B chunks, so the old LDS round-trip was a pure copy
// with a serial global->vmcnt->ds_write->lgkm->ds_read chain per kt. LDS now 27.6 KB.
__global__ __launch_bounds__(512, 4) void qkv_kernel(
    const float* __restrict__ x, const unsigned short* __restrict__ Wt,
    unsigned short* __restrict__ qb, unsigned short* __restrict__ kb,
    unsigned short* __restrict__ vtb)
{
    __shared__ __align__(16) unsigned short lds[13824];  // max(x-staging 4608, epilogue 13824)
    unsigned short* xs0 = lds;           // x tile 32 x 64, pad 72 (buf 0)
    unsigned short* xs1 = lds + 2304;    // buf 1

    const int t    = threadIdx.x;
    const int lane = t & 63, ng = t >> 6;
    const int quad = lane >> 4, l16 = lane & 15;
    const int m0   = blockIdx.x * 32;

    f32x4 acc[2][3];
#pragma unroll
    for (int i = 0; i < 2; ++i)
#pragma unroll
        for (int j = 0; j < 3; ++j) acc[i][j] = (f32x4){0.f, 0.f, 0.f, 0.f};

    const int xrow = t >> 4, xseg = t & 15;   // all 512 threads stage 4 floats each
    {   // prologue: stage x(kt=0)
        float4 a = *(const float4*)&x[(size_t)(m0 + xrow) * EMB + xseg * 4];
        short4v p;
        p[0] = (short)f2bf(a.x); p[1] = (short)f2bf(a.y);
        p[2] = (short)f2bf(a.z); p[3] = (short)f2bf(a.w);
        *(short4v*)&xs0[xrow * 72 + xseg * 4] = p;
    }
    __syncthreads();

    // per-lane W base: row = ng*48 + l16 (+ jt*16), col chunk quad*8
    const unsigned short* Wb = Wt + ((size_t)(ng * 48 + l16)) * 1024 + quad * 8;

    for (int kt = 0; kt < EMB; kt += 64) {
        unsigned short* xb = (kt & 64) ? xs1 : xs0;
        unsigned short* xn = (kt & 64) ? xs0 : xs1;
        // prefetch next x tile into the other buffer
        if (kt + 64 < EMB) {
            float4 a = *(const float4*)&x[(size_t)(m0 + xrow) * EMB + kt + 64 + xseg * 4];
            short4v p;
            p[0] = (short)f2bf(a.x); p[1] = (short)f2bf(a.y);
            p[2] = (short)f2bf(a.z); p[3] = (short)f2bf(a.w);
            *(short4v*)&xn[xrow * 72 + xseg * 4] = p;
        }
        // B frags direct from global (L2-hot); A frags from LDS
        bf16x8 aB[2][3], aA[2][2];
#pragma unroll
        for (int ks = 0; ks < 2; ++ks)
#pragma unroll
            for (int jt = 0; jt < 3; ++jt)
                aB[ks][jt] = *(const bf16x8*)&Wb[(size_t)jt * 16 * 1024 + kt + ks * 32];
#pragma unroll
        for (int ks = 0; ks < 2; ++ks)
#pragma unroll
            for (int mt = 0; mt < 2; ++mt)
                aA[ks][mt] = *(const bf16x8*)&xb[(mt * 16 + l16) * 72 + ks * 32 + quad * 8];
        __builtin_amdgcn_s_setprio(1);
#pragma unroll
        for (int ks = 0; ks < 2; ++ks)
#pragma unroll
            for (int mt = 0; mt < 2; ++mt)
#pragma unroll
                for (int jt = 0; jt < 3; ++jt)
                    acc[mt][jt] = __builtin_amdgcn_mfma_f32_16x16x32_bf16(
                        aA[ks][mt], aB[ks][jt], acc[mt][jt], 0, 0, 0);
        __builtin_amdgcn_s_setprio(0);
        __syncthreads();
    }

    // ---- epilogue: scatter to LDS (per-matrix layout), then coalesced copy out ----
    unsigned short* Cq = lds;                 // [32][136]
    unsigned short* Ck = lds + 32 * 136;      // [32][136]
    unsigned short* Cv = lds + 2 * 32 * 136;  // [128][40] transposed
#pragma unroll
    for (int mt = 0; mt < 2; ++mt)
#pragma unroll
        for (int jt = 0; jt < 3; ++jt) {
            int nt = ng * 3 + jt;
            int wm = nt >> 3, nl = nt & 7;
            if (wm < 2) {
                unsigned short* C = (wm == 0) ? Cq : Ck;
#pragma unroll
                for (int rr = 0; rr < 4; ++rr)
                    C[(mt * 16 + quad * 4 + rr) * 136 + nl * 16 + l16] =
                        f2bf(acc[mt][jt][rr]);
            } else {
                short4v p;
                p[0] = (short)f2bf(acc[mt][jt][0]); p[1] = (short)f2bf(acc[mt][jt][1]);
                p[2] = (short)f2bf(acc[mt][jt][2]); p[3] = (short)f2bf(acc[mt][jt][3]);
                *(short4v*)&Cv[(nl * 16 + l16) * 40 + mt * 16 + quad * 4] = p;
            }
        }
    __syncthreads();
    {   // q, k: 32 x 128 each -> 512 i32x4, one per thread
        int row = t >> 4, seg = t & 15;
        *(i32x4*)&qb[((size_t)(m0 + row)) * HD + seg * 8] = *(const i32x4*)&Cq[row * 136 + seg * 8];
        *(i32x4*)&kb[((size_t)(m0 + row)) * HD + seg * 8] = *(const i32x4*)&Ck[row * 136 + seg * 8];
    }
    {   // v^T: 128 x 32 -> 512 i32x4, one per thread
        const int b = m0 >> 12, s0 = m0 & 4095;
        int h = t >> 2, seg = t & 3;
        *(i32x4*)&vtb[(size_t)b * (HD * SEQ) + (size_t)h * SEQ + s0 + seg * 8] =
            *(const i32x4*)&Cv[h * 40 + seg * 8];
    }
}

// ---------------- Flash attention: split-KV, BQ=128, 8 waves, XCD-batch affinity ----------------
// grid 480 x 512 thr. bx -> slot=bx&7 (≈XCD), batch=slot>>1, jj=(bx>>3)*2+(slot&1).
// Each XCD sees one batch -> K/V (4 MB) stays L2-resident.
// T14 async-stage: next tile's K/V loaded into regs before compute, written after barrier.
// exp2-domain online softmax (scores pre-scaled by log2e via Wq) + T13 defer-max.
#define PADK 136
#define PADV 72
#define PADP 72
#define DEFER_THR 8.0f   // log2 domain: P bounded by 2^8=256, safe in bf16/f32

__global__ __launch_bounds__(512, 4) void flash_kernel(
    const unsigned short* __restrict__ qb, const unsigned short* __restrict__ kb,
    const unsigned short* __restrict__ vtb, unsigned short* __restrict__ Opart,
    float* __restrict__ mbuf, float* __restrict__ lbuf)
{
    __shared__ __align__(16) unsigned short Ks[64 * PADK];    // 17.4 KB
    __shared__ __align__(16) unsigned short Vt[128 * PADV];   // 18.4 KB
    __shared__ __align__(16) unsigned short Pt[128 * PADP];   // 18.4 KB

    const int bx   = blockIdx.x;
    const int slot = bx & 7, pp = bx >> 3;
    const int b    = slot >> 1;
    const int jj   = pp * 2 + (slot & 1);
    if (jj >= NJOBS) return;                 // dummy pad blocks (no barrier yet)

    const int t    = threadIdx.x;
    const int lane = t & 63, w = t >> 6;     // 8 waves
    const int quad = lane >> 4, l16 = lane & 15;

    // decode jj -> (qi, c): q-tile qi has ceil((qi+1)/5) chunks
    int qi = 0, s = 0;
    for (qi = 0; qi < 32; ++qi) {
        int cnt = (qi + 5) / 5;
        if (jj < s + cnt) break;
        s += cnt;
    }
    const int c    = jj - s;
    const int qrow = qi * 128 + w * 16 + l16;
    const int jmax = 2 * qi + 2;
    const int jbeg = c * CHUNK;
    const int jend = min(jbeg + CHUNK, jmax);
    const int wtop = qi * 128 + w * 16;      // wave's lowest q-row

    bf16x8 qf[4];
    {
        const unsigned short* qp = qb + ((size_t)b * SEQ + qrow) * HD;
#pragma unroll
        for (int ks = 0; ks < 4; ++ks)
            qf[ks] = *(const bf16x8*)&qp[ks * 32 + quad * 8];
    }

    f32x4 O[8];
#pragma unroll
    for (int i = 0; i < 8; ++i) O[i] = (f32x4){0.f, 0.f, 0.f, 0.f};
    float m_run = -1e30f, l_run = 0.f;

    const unsigned short* kbb  = kb  + (size_t)b * SEQ * HD;
    const unsigned short* vtbb = vtb + (size_t)b * HD * SEQ;

    const int gg0 = t, gg1 = 512 + t;
    // prologue: load first tile into regs
    i32x4 kr0, kr1, vr0, vr1;
    kr0 = *(const i32x4*)&kbb[(size_t)jbeg * 64 * HD + (size_t)gg0 * 8];
    kr1 = *(const i32x4*)&kbb[(size_t)jbeg * 64 * HD + (size_t)gg1 * 8];
    vr0 = *(const i32x4*)&vtbb[(size_t)(gg0 >> 3) * SEQ + jbeg * 64 + (gg0 & 7) * 8];
    vr1 = *(const i32x4*)&vtbb[(size_t)(gg1 >> 3) * SEQ + jbeg * 64 + (gg1 & 7) * 8];

    for (int j0 = jbeg; j0 < jend; ++j0) {
        __syncthreads();   // prior iteration's reads of Ks/Vt complete (WAR)
        // write prefetched tile (vmcnt drained here, hidden under prior compute)
        *(i32x4*)&Ks[(gg0 >> 4) * PADK + (gg0 & 15) * 8] = kr0;
        *(i32x4*)&Ks[(gg1 >> 4) * PADK + (gg1 & 15) * 8] = kr1;
        *(i32x4*)&Vt[(gg0 >> 3) * PADV + (gg0 & 7) * 8] = vr0;
        *(i32x4*)&Vt[(gg1 >> 3) * PADV + (gg1 & 7) * 8] = vr1;
        __syncthreads();

        // issue next tile's loads NOW — latency hides under this tile's compute
        if (j0 + 1 < jend) {
            const int j1 = j0 + 1;
            kr0 = *(const i32x4*)&kbb[(size_t)j1 * 64 * HD + (size_t)gg0 * 8];
            kr1 = *(const i32x4*)&kbb[(size_t)j1 * 64 * HD + (size_t)gg1 * 8];
            vr0 = *(const i32x4*)&vtbb[(size_t)(gg0 >> 3) * SEQ + j1 * 64 + (gg0 & 7) * 8];
            vr1 = *(const i32x4*)&vtbb[(size_t)(gg1 >> 3) * SEQ + j1 * 64 + (gg1 & 7) * 8];
        }

        // fully-masked tile for this wave? -> skip compute (loads already issued)
        if (j0 * 64 > wtop + 15) continue;

        // ---- S^T = K . Q^T ----
        f32x4 st[4];
        __builtin_amdgcn_s_setprio(1);
#pragma unroll
        for (int mt = 0; mt < 4; ++mt) {
            f32x4 a = (f32x4){0.f, 0.f, 0.f, 0.f};
#pragma unroll
            for (int ks = 0; ks < 4; ++ks) {
                bf16x8 kf = *(const bf16x8*)&Ks[(mt * 16 + l16) * PADK + ks * 32 + quad * 8];
                a = __builtin_amdgcn_mfma_f32_16x16x32_bf16(kf, qf[ks], a, 0, 0, 0);
            }
            st[mt] = a;
        }
        __builtin_amdgcn_s_setprio(0);

        // ---- causal mask (skip when tile fully valid for this wave) ----
        if (j0 * 64 + 63 > wtop) {
#pragma unroll
            for (int mt = 0; mt < 4; ++mt)
#pragma unroll
                for (int rr = 0; rr < 4; ++rr) {
                    int kv = j0 * 64 + mt * 16 + quad * 4 + rr;
                    if (kv > qrow) st[mt][rr] = -1e30f;
                }
        }
        // NOTE: rows with zero valid entries yield m=-1e30 garbage partials;
        // combine neutralizes them via wgt = exp2(-1e30 - M) = 0.

        // ---- online softmax, exp2 domain (lane owns one q-row) ----
        float mx = -1e30f;
#pragma unroll
        for (int mt = 0; mt < 4; ++mt)
#pragma unroll
            for (int rr = 0; rr < 4; ++rr) mx = fmaxf(mx, st[mt][rr]);
        mx = fmaxf(mx, __shfl_xor(mx, 16));
        mx = fmaxf(mx, __shfl_xor(mx, 32));
        // T13 defer-max: only rescale when the wave's max grew past THR
        if (!__all(mx <= m_run + DEFER_THR)) {
            const float m_new = fmaxf(m_run, mx);
            const float alpha = exp2f(m_run - m_new);
            l_run *= alpha;
#pragma unroll
            for (int i = 0; i < 8; ++i) {
                O[i][0] *= alpha; O[i][1] *= alpha; O[i][2] *= alpha; O[i][3] *= alpha;
            }
            m_run = m_new;
        }
        float psum = 0.f;
#pragma unroll
        for (int mt = 0; mt < 4; ++mt)
#pragma unroll
            for (int rr = 0; rr < 4; ++rr) {
                float p = exp2f(st[mt][rr] - m_run);
                st[mt][rr] = p;
                psum += p;
            }
        psum += __shfl_xor(psum, 16);
        psum += __shfl_xor(psum, 32);
        l_run += psum;

        // ---- P^T -> LDS (wave-private rows; no barrier needed) ----
#pragma unroll
        for (int mt = 0; mt < 4; ++mt) {
            short4v p;
            p[0] = (short)f2bf(st[mt][0]); p[1] = (short)f2bf(st[mt][1]);
            p[2] = (short)f2bf(st[mt][2]); p[3] = (short)f2bf(st[mt][3]);
            *(short4v*)&Pt[(w * 16 + l16) * PADP + mt * 16 + quad * 4] = p;
        }

        // ---- O^T += V^T . P^T ----
        bf16x8 pf0 = *(const bf16x8*)&Pt[(w * 16 + l16) * PADP + quad * 8];
        bf16x8 pf1 = *(const bf16x8*)&Pt[(w * 16 + l16) * PADP + 32 + quad * 8];
        __builtin_amdgcn_s_setprio(1);
#pragma unroll
        for (int mt = 0; mt < 8; ++mt) {
            bf16x8 vf0 = *(const bf16x8*)&Vt[(mt * 16 + l16) * PADV + quad * 8];
            bf16x8 vf1 = *(const bf16x8*)&Vt[(mt * 16 + l16) * PADV + 32 + quad * 8];
            O[mt] = __builtin_amdgcn_mfma_f32_16x16x32_bf16(vf0, pf0, O[mt], 0, 0, 0);
            O[mt] = __builtin_amdgcn_mfma_f32_16x16x32_bf16(vf1, pf1, O[mt], 0, 0, 0);
        }
        __builtin_amdgcn_s_setprio(0);
    }

    // ---- partial epilogue: unnormalized O (bf16) + m,l (log2 domain) ----
    const int r = w * 16 + l16;
    const size_t jobbase = (size_t)b * NJOBS + jj;
    unsigned short* po = Opart + jobbase * (128 * 128) + (size_t)r * 128;
#pragma unroll
    for (int mt = 0; mt < 8; ++mt) {
        short4v p;
        p[0] = (short)f2bf(O[mt][0]); p[1] = (short)f2bf(O[mt][1]);
        p[2] = (short)f2bf(O[mt][2]); p[3] = (short)f2bf(O[mt][3]);
        *(short4v*)&po[mt * 16 + quad * 4] = p;
    }
    if (quad == 0) {
        mbuf[jobbase * 128 + r] = m_run;
        lbuf[jobbase * 128 + r] = l_run;
    }
}

// ---------------- Combine partials (log2-domain m) ----------------
// grid (32, 4) x 512 thr: thread -> q-row t>>2 (0..127), 32 head cols at (t&3)*32.
__global__ __launch_bounds__(512) void combine_kernel(
    const unsigned short* __restrict__ Opart, const float* __restrict__ mbuf,
    const float* __restrict__ lbuf, float* __restrict__ out)
{
    const int qi = blockIdx.x, b = blockIdx.y;
    const int nc = (qi + 5) / 5;
    int j0 = 0;
    for (int q = 0; q < qi; ++q) j0 += (q + 5) / 5;
    const int t = threadIdx.x;
    const int row = t >> 2, cg = (t & 3) * 32;

    float mv[MAXC], lv[MAXC];
    float M = -1e30f;
#pragma unroll
    for (int c2 = 0; c2 < MAXC; ++c2) {
        if (c2 < nc) {
            const size_t jb = (size_t)b * NJOBS + j0 + c2;
            mv[c2] = mbuf[jb * 128 + row];
            lv[c2] = lbuf[jb * 128 + row];
            M = fmaxf(M, mv[c2]);
        } else { mv[c2] = -1e30f; lv[c2] = 0.f; }
    }
    float L = 0.f;
#pragma unroll
    for (int c2 = 0; c2 < MAXC; ++c2)
        if (c2 < nc) L += exp2f(mv[c2] - M) * lv[c2];
    const float Linv = 1.0f / L;

    float acc[32];
#pragma unroll
    for (int i = 0; i < 32; ++i) acc[i] = 0.f;
#pragma unroll
    for (int c2 = 0; c2 < MAXC; ++c2) {
        if (c2 < nc) {
            const float wgt = exp2f(mv[c2] - M) * Linv;
            const unsigned short* po = Opart + ((size_t)b * NJOBS + j0 + c2) * (128 * 128) +
                                       (size_t)row * 128 + cg;
#pragma unroll
            for (int i = 0; i < 4; ++i) {
                i32x4 d = *(const i32x4*)&po[i * 8];
#pragma unroll
                for (int e = 0; e < 4; ++e) {
                    unsigned int u = (unsigned int)d[e];
                    acc[i * 8 + e * 2]     = fmaf(wgt, bf2f((unsigned short)(u & 0xffff)), acc[i * 8 + e * 2]);
                    acc[i * 8 + e * 2 + 1] = fmaf(wgt, bf2f((unsigned short)(u >> 16)),   acc[i * 8 + e * 2 + 1]);
                }
            }
        }
    }
    float* op = out + ((size_t)b * SEQ + qi * 128 + row) * HD + cg;
#pragma unroll
    for (int i = 0; i < 8; ++i) {
        float4 res;
        res.x = acc[i * 4]; res.y = acc[i * 4 + 1];
        res.z = acc[i * 4 + 2]; res.w = acc[i * 4 + 3];
        *(float4*)&op[i * 4] = res;
    }
}

extern "C" void kernel_launch(void* const* d_in, const int* in_sizes, int n_in,
                              void* d_out, int out_size, void* d_ws, size_t ws_size,
                              hipStream_t stream) {
    const float* x  = (const float*)d_in[0];
    const float* Wq = (const float*)d_in[1];
    const float* Wk = (const float*)d_in[2];
    const float* Wv = (const float*)d_in[3];

    unsigned short* qb    = (unsigned short*)d_ws;          // [16384][128] bf16
    unsigned short* kb    = qb  + (size_t)MROWS * HD;       // [16384][128] bf16
    unsigned short* vtb   = kb  + (size_t)MROWS * HD;       // [4][128][4096] bf16
    unsigned short* Wt    = vtb + (size_t)MROWS * HD;       // [3][128][1024] bf16
    unsigned short* Opart = Wt  + (size_t)3 * HD * EMB;     // [4][119][128][128] bf16
    float* mbuf = (float*)(Opart + (size_t)BATCH * NJOBS * 128 * 128);
    float* lbuf = mbuf + (size_t)BATCH * NJOBS * 128;
    float* out = (float*)d_out;

    wtrans_kernel <<<dim3(64, 3),  dim3(256), 0, stream>>>(Wq, Wk, Wv, Wt);
    qkv_kernel    <<<dim3(512),    dim3(512), 0, stream>>>(x, Wt, qb, kb, vtb);
    flash_kernel  <<<dim3(480),    dim3(512), 0, stream>>>(qb, kb, vtb, Opart, mbuf, lbuf);
    combine_kernel<<<dim3(32, 4),  dim3(512), 0, stream>>>(Opart, mbuf, lbuf, out);
}

// Round 2
// 188.043 us; speedup vs baseline: 1.0136x; 1.0136x over previous
//
#include <hip/hip_runtime.h>
#include <math.h>

#define BATCH 4
#define SEQ   4096
#define EMB   1024
#define HD    128
#define MROWS (BATCH*SEQ)
#define SCALE  0.08838834764831844f   // 1/sqrt(128)
#define SCALEQ 0.12751742f            // (1/sqrt(128)) * log2(e)  -> exp2-domain scores
#define CHUNK 10                      // kv-tiles (of 64) per split-KV job
#define NJOBS 119                     // jobs per batch at BQ=128, CHUNK=10
#define MAXC  7                       // max chunks per q-tile = ceil(64/10)

typedef __attribute__((ext_vector_type(8))) short bf16x8;   // MFMA A/B frag (4 VGPR)
typedef __attribute__((ext_vector_type(4))) short short4v;  // 8B LDS store
typedef __attribute__((ext_vector_type(4))) float f32x4;    // MFMA C/D frag
typedef __attribute__((ext_vector_type(4))) int   i32x4;    // 16B copy

static __device__ __forceinline__ unsigned short f2bf(float f) {
    unsigned int u = __float_as_uint(f);
    u += 0x7fff + ((u >> 16) & 1);       // RNE
    return (unsigned short)(u >> 16);
}
static __device__ __forceinline__ float bf2f(unsigned short s) {
    return __uint_as_float((unsigned int)s << 16);
}
static __device__ __forceinline__ short4v pack4(float4 a) {
    short4v p;
    p[0] = (short)f2bf(a.x); p[1] = (short)f2bf(a.y);
    p[2] = (short)f2bf(a.z); p[3] = (short)f2bf(a.w);
    return p;
}

// ---------------- W transpose + bf16 (+ fold q-scale * log2e) ----------------
// grid (64, 3) x 256 thr. Block: 16 k-rows x 128 n of one matrix, via LDS transpose.
__global__ __launch_bounds__(256) void wtrans_kernel(
    const float* __restrict__ Wq, const float* __restrict__ Wk,
    const float* __restrict__ Wv, unsigned short* __restrict__ Wt)
{
    __shared__ __align__(16) unsigned short Xs[16 * 132];
    const int w  = blockIdx.y;
    const float* W = (w == 0) ? Wq : (w == 1) ? Wk : Wv;
    const float sc = (w == 0) ? SCALEQ : 1.0f;   // exp2-domain: scores carry log2(e)
    unsigned short* dst = Wt + (size_t)w * 131072;
    const int k0 = blockIdx.x * 16;
    const int t  = threadIdx.x;

#pragma unroll
    for (int i = 0; i < 2; ++i) {
        int gg = i * 256 + t;                 // 0..511
        int row = gg >> 5, c4 = gg & 31;
        float4 a = *(const float4*)&W[(size_t)(k0 + row) * HD + c4 * 4];
        short4v p;
        p[0] = (short)f2bf(a.x * sc); p[1] = (short)f2bf(a.y * sc);
        p[2] = (short)f2bf(a.z * sc); p[3] = (short)f2bf(a.w * sc);
        *(short4v*)&Xs[row * 132 + c4 * 4] = p;
    }
    __syncthreads();
    const int n = t >> 1, half = t & 1;
    i32x4 o;
#pragma unroll
    for (int e = 0; e < 4; ++e) {
        unsigned int lo = Xs[(half * 8 + e * 2    ) * 132 + n];
        unsigned int hi = Xs[(half * 8 + e * 2 + 1) * 132 + n];
        o[e] = (int)(lo | (hi << 16));
    }
    *(i32x4*)&dst[(size_t)n * 1024 + k0 + half * 8] = o;
}

// ---------------- Fused QKV: W frags in registers, double-buffered one kt ahead ----------------
// grid 512 x 512 thr (8 waves). Wave ng owns n-tiles 3ng..3ng+2 (48 W rows).
// B-fragments load DIRECTLY from Wt (L2-resident) into regs with one-kt prefetch
// distance (round-1 failure: same loads with zero distance -> L2 latency on the
// MFMA critical path, 60us, MfmaUtil 7%). Two-phase unrolled loop, named aB0/aB1
// (no runtime-indexed frag arrays -> no scratch). x double-buffered in LDS.
// Per phase, program order: x global load FIRST, then 6 W loads, then x ds_write
// (vmcnt wait leaves W loads in flight), then ds_read A + MFMA on prev-phase W regs.
__global__ __launch_bounds__(512, 4) void qkv_kernel(
    const float* __restrict__ x, const unsigned short* __restrict__ Wt,
    unsigned short* __restrict__ qb, unsigned short* __restrict__ kb,
    unsigned short* __restrict__ vtb)
{
    __shared__ __align__(16) unsigned short lds[13824];  // max(x dbuf 4608, epilogue 13824)
    unsigned short* xs0 = lds;           // x tile 32 x 64, pad 72 (buf 0)
    unsigned short* xs1 = lds + 2304;    // buf 1

    const int t    = threadIdx.x;
    const int lane = t & 63, ng = t >> 6;
    const int quad = lane >> 4, l16 = lane & 15;
    const int m0   = blockIdx.x * 32;

    f32x4 acc[2][3];
#pragma unroll
    for (int i = 0; i < 2; ++i)
#pragma unroll
        for (int j = 0; j < 3; ++j) acc[i][j] = (f32x4){0.f, 0.f, 0.f, 0.f};

    const int xrow = t >> 4, xseg = t & 15;   // all 512 threads stage 4 floats each
    const float* xbase = x + (size_t)(m0 + xrow) * EMB + xseg * 4;
    // per-lane W base: row = ng*48 + jt*16 + l16, col chunk quad*8
    const unsigned short* Wb = Wt + ((size_t)(ng * 48 + l16)) * 1024 + quad * 8;

    bf16x8 aB0[2][3], aB1[2][3];

    // prologue: stage x(kt=0) + load W frags for kt=0
    {
        float4 a = *(const float4*)&xbase[0];
#pragma unroll
        for (int ks = 0; ks < 2; ++ks)
#pragma unroll
            for (int jt = 0; jt < 3; ++jt)
                aB0[ks][jt] = *(const bf16x8*)&Wb[(size_t)jt * 16384 + ks * 32];
        *(short4v*)&xs0[xrow * 72 + xseg * 4] = pack4(a);
    }
    __syncthreads();

    for (int kt = 0; kt < EMB; kt += 128) {
        // ---- phase A: compute kt (xs0, aB0); prefetch kt+64 (xs1, aB1) ----
        {
            float4 a = *(const float4*)&xbase[kt + 64];          // issue x first
#pragma unroll
            for (int ks = 0; ks < 2; ++ks)
#pragma unroll
                for (int jt = 0; jt < 3; ++jt)                    // then W (stay in flight)
                    aB1[ks][jt] = *(const bf16x8*)&Wb[(size_t)jt * 16384 + kt + 64 + ks * 32];
            *(short4v*)&xs1[xrow * 72 + xseg * 4] = pack4(a);     // waits x only
        }
        {
            bf16x8 aA[2][2];
#pragma unroll
            for (int ks = 0; ks < 2; ++ks)
#pragma unroll
                for (int mt = 0; mt < 2; ++mt)
                    aA[ks][mt] = *(const bf16x8*)&xs0[(mt * 16 + l16) * 72 + ks * 32 + quad * 8];
            __builtin_amdgcn_s_setprio(1);
#pragma unroll
            for (int ks = 0; ks < 2; ++ks)
#pragma unroll
                for (int mt = 0; mt < 2; ++mt)
#pragma unroll
                    for (int jt = 0; jt < 3; ++jt)
                        acc[mt][jt] = __builtin_amdgcn_mfma_f32_16x16x32_bf16(
                            aA[ks][mt], aB0[ks][jt], acc[mt][jt], 0, 0, 0);
            __builtin_amdgcn_s_setprio(0);
        }
        __syncthreads();

        // ---- phase B: compute kt+64 (xs1, aB1); prefetch kt+128 (xs0, aB0) ----
        if (kt + 128 < EMB) {
            float4 a = *(const float4*)&xbase[kt + 128];
#pragma unroll
            for (int ks = 0; ks < 2; ++ks)
#pragma unroll
                for (int jt = 0; jt < 3; ++jt)
                    aB0[ks][jt] = *(const bf16x8*)&Wb[(size_t)jt * 16384 + kt + 128 + ks * 32];
            *(short4v*)&xs0[xrow * 72 + xseg * 4] = pack4(a);
        }
        {
            bf16x8 aA[2][2];
#pragma unroll
            for (int ks = 0; ks < 2; ++ks)
#pragma unroll
                for (int mt = 0; mt < 2; ++mt)
                    aA[ks][mt] = *(const bf16x8*)&xs1[(mt * 16 + l16) * 72 + ks * 32 + quad * 8];
            __builtin_amdgcn_s_setprio(1);
#pragma unroll
            for (int ks = 0; ks < 2; ++ks)
#pragma unroll
                for (int mt = 0; mt < 2; ++mt)
#pragma unroll
                    for (int jt = 0; jt < 3; ++jt)
                        acc[mt][jt] = __builtin_amdgcn_mfma_f32_16x16x32_bf16(
                            aA[ks][mt], aB1[ks][jt], acc[mt][jt], 0, 0, 0);
            __builtin_amdgcn_s_setprio(0);
        }
        __syncthreads();
    }

    // ---- epilogue: scatter to LDS (per-matrix layout), then coalesced copy out ----
    unsigned short* Cq = lds;                 // [32][136]
    unsigned short* Ck = lds + 32 * 136;      // [32][136]
    unsigned short* Cv = lds + 2 * 32 * 136;  // [128][40] transposed
#pragma unroll
    for (int mt = 0; mt < 2; ++mt)
#pragma unroll
        for (int jt = 0; jt < 3; ++jt) {
            int nt = ng * 3 + jt;
            int wm = nt >> 3, nl = nt & 7;
            if (wm < 2) {
                unsigned short* C = (wm == 0) ? Cq : Ck;
#pragma unroll
                for (int rr = 0; rr < 4; ++rr)
                    C[(mt * 16 + quad * 4 + rr) * 136 + nl * 16 + l16] =
                        f2bf(acc[mt][jt][rr]);
            } else {
                short4v p;
                p[0] = (short)f2bf(acc[mt][jt][0]); p[1] = (short)f2bf(acc[mt][jt][1]);
                p[2] = (short)f2bf(acc[mt][jt][2]); p[3] = (short)f2bf(acc[mt][jt][3]);
                *(short4v*)&Cv[(nl * 16 + l16) * 40 + mt * 16 + quad * 4] = p;
            }
        }
    __syncthreads();
    {   // q, k: 32 x 128 each -> 512 i32x4, one per thread
        int row = t >> 4, seg = t & 15;
        *(i32x4*)&qb[((size_t)(m0 + row)) * HD + seg * 8] = *(const i32x4*)&Cq[row * 136 + seg * 8];
        *(i32x4*)&kb[((size_t)(m0 + row)) * HD + seg * 8] = *(const i32x4*)&Ck[row * 136 + seg * 8];
    }
    {   // v^T: 128 x 32 -> 512 i32x4, one per thread
        const int b = m0 >> 12, s0 = m0 & 4095;
        int h = t >> 2, seg = t & 3;
        *(i32x4*)&vtb[(size_t)b * (HD * SEQ) + (size_t)h * SEQ + s0 + seg * 8] =
            *(const i32x4*)&Cv[h * 40 + seg * 8];
    }
}

// ---------------- Flash attention: split-KV, BQ=128, 8 waves, XCD-batch affinity ----------------
// grid 480 x 512 thr. bx -> slot=bx&7 (≈XCD), batch=slot>>1, jj=(bx>>3)*2+(slot&1).
// Each XCD sees one batch -> K/V (4 MB) stays L2-resident.
// T14 async-stage: next tile's K/V loaded into regs before compute, written after barrier.
// exp2-domain online softmax (scores pre-scaled by log2e via Wq) + T13 defer-max.
#define PADK 136
#define PADV 72
#define PADP 72
#define DEFER_THR 8.0f   // log2 domain: P bounded by 2^8=256, safe in bf16/f32

__global__ __launch_bounds__(512, 4) void flash_kernel(
    const unsigned short* __restrict__ qb, const unsigned short* __restrict__ kb,
    const unsigned short* __restrict__ vtb, unsigned short* __restrict__ Opart,
    float* __restrict__ mbuf, float* __restrict__ lbuf)
{
    __shared__ __align__(16) unsigned short Ks[64 * PADK];    // 17.4 KB
    __shared__ __align__(16) unsigned short Vt[128 * PADV];   // 18.4 KB
    __shared__ __align__(16) unsigned short Pt[128 * PADP];   // 18.4 KB

    const int bx   = blockIdx.x;
    const int slot = bx & 7, pp = bx >> 3;
    const int b    = slot >> 1;
    const int jj   = pp * 2 + (slot & 1);
    if (jj >= NJOBS) return;                 // dummy pad blocks (no barrier yet)

    const int t    = threadIdx.x;
    const int lane = t & 63, w = t >> 6;     // 8 waves
    const int quad = lane >> 4, l16 = lane & 15;

    // decode jj -> (qi, c): q-tile qi has ceil((qi+1)/5) chunks
    int qi = 0, s = 0;
    for (qi = 0; qi < 32; ++qi) {
        int cnt = (qi + 5) / 5;
        if (jj < s + cnt) break;
        s += cnt;
    }
    const int c    = jj - s;
    const int qrow = qi * 128 + w * 16 + l16;
    const int jmax = 2 * qi + 2;
    const int jbeg = c * CHUNK;
    const int jend = min(jbeg + CHUNK, jmax);
    const int wtop = qi * 128 + w * 16;      // wave's lowest q-row

    bf16x8 qf[4];
    {
        const unsigned short* qp = qb + ((size_t)b * SEQ + qrow) * HD;
#pragma unroll
        for (int ks = 0; ks < 4; ++ks)
            qf[ks] = *(const bf16x8*)&qp[ks * 32 + quad * 8];
    }

    f32x4 O[8];
#pragma unroll
    for (int i = 0; i < 8; ++i) O[i] = (f32x4){0.f, 0.f, 0.f, 0.f};
    float m_run = -1e30f, l_run = 0.f;

    const unsigned short* kbb  = kb  + (size_t)b * SEQ * HD;
    const unsigned short* vtbb = vtb + (size_t)b * HD * SEQ;

    const int gg0 = t, gg1 = 512 + t;
    // prologue: load first tile into regs
    i32x4 kr0, kr1, vr0, vr1;
    kr0 = *(const i32x4*)&kbb[(size_t)jbeg * 64 * HD + (size_t)gg0 * 8];
    kr1 = *(const i32x4*)&kbb[(size_t)jbeg * 64 * HD + (size_t)gg1 * 8];
    vr0 = *(const i32x4*)&vtbb[(size_t)(gg0 >> 3) * SEQ + jbeg * 64 + (gg0 & 7) * 8];
    vr1 = *(const i32x4*)&vtbb[(size_t)(gg1 >> 3) * SEQ + jbeg * 64 + (gg1 & 7) * 8];

    for (int j0 = jbeg; j0 < jend; ++j0) {
        __syncthreads();   // prior iteration's reads of Ks/Vt complete (WAR)
        // write prefetched tile (vmcnt drained here, hidden under prior compute)
        *(i32x4*)&Ks[(gg0 >> 4) * PADK + (gg0 & 15) * 8] = kr0;
        *(i32x4*)&Ks[(gg1 >> 4) * PADK + (gg1 & 15) * 8] = kr1;
        *(i32x4*)&Vt[(gg0 >> 3) * PADV + (gg0 & 7) * 8] = vr0;
        *(i32x4*)&Vt[(gg1 >> 3) * PADV + (gg1 & 7) * 8] = vr1;
        __syncthreads();

        // issue next tile's loads NOW — latency hides under this tile's compute
        if (j0 + 1 < jend) {
            const int j1 = j0 + 1;
            kr0 = *(const i32x4*)&kbb[(size_t)j1 * 64 * HD + (size_t)gg0 * 8];
            kr1 = *(const i32x4*)&kbb[(size_t)j1 * 64 * HD + (size_t)gg1 * 8];
            vr0 = *(const i32x4*)&vtbb[(size_t)(gg0 >> 3) * SEQ + j1 * 64 + (gg0 & 7) * 8];
            vr1 = *(const i32x4*)&vtbb[(size_t)(gg1 >> 3) * SEQ + j1 * 64 + (gg1 & 7) * 8];
        }

        // fully-masked tile for this wave? -> skip compute (loads already issued)
        if (j0 * 64 > wtop + 15) continue;

        // ---- S^T = K . Q^T ----
        f32x4 st[4];
        __builtin_amdgcn_s_setprio(1);
#pragma unroll
        for (int mt = 0; mt < 4; ++mt) {
            f32x4 a = (f32x4){0.f, 0.f, 0.f, 0.f};
#pragma unroll
            for (int ks = 0; ks < 4; ++ks) {
                bf16x8 kf = *(const bf16x8*)&Ks[(mt * 16 + l16) * PADK + ks * 32 + quad * 8];
                a = __builtin_amdgcn_mfma_f32_16x16x32_bf16(kf, qf[ks], a, 0, 0, 0);
            }
            st[mt] = a;
        }
        __builtin_amdgcn_s_setprio(0);

        // ---- causal mask (skip when tile fully valid for this wave) ----
        if (j0 * 64 + 63 > wtop) {
#pragma unroll
            for (int mt = 0; mt < 4; ++mt)
#pragma unroll
                for (int rr = 0; rr < 4; ++rr) {
                    int kv = j0 * 64 + mt * 16 + quad * 4 + rr;
                    if (kv > qrow) st[mt][rr] = -1e30f;
                }
        }
        // NOTE: rows with zero valid entries yield m=-1e30 garbage partials;
        // combine neutralizes them via wgt = exp2(-1e30 - M) = 0.

        // ---- online softmax, exp2 domain (lane owns one q-row) ----
        float mx = -1e30f;
#pragma unroll
        for (int mt = 0; mt < 4; ++mt)
#pragma unroll
            for (int rr = 0; rr < 4; ++rr) mx = fmaxf(mx, st[mt][rr]);
        mx = fmaxf(mx, __shfl_xor(mx, 16));
        mx = fmaxf(mx, __shfl_xor(mx, 32));
        // T13 defer-max: only rescale when the wave's max grew past THR
        if (!__all(mx <= m_run + DEFER_THR)) {
            const float m_new = fmaxf(m_run, mx);
            const float alpha = exp2f(m_run - m_new);
            l_run *= alpha;
#pragma unroll
            for (int i = 0; i < 8; ++i) {
                O[i][0] *= alpha; O[i][1] *= alpha; O[i][2] *= alpha; O[i][3] *= alpha;
            }
            m_run = m_new;
        }
        float psum = 0.f;
#pragma unroll
        for (int mt = 0; mt < 4; ++mt)
#pragma unroll
            for (int rr = 0; rr < 4; ++rr) {
                float p = exp2f(st[mt][rr] - m_run);
                st[mt][rr] = p;
                psum += p;
            }
        psum += __shfl_xor(psum, 16);
        psum += __shfl_xor(psum, 32);
        l_run += psum;

        // ---- P^T -> LDS (wave-private rows; no barrier needed) ----
#pragma unroll
        for (int mt = 0; mt < 4; ++mt) {
            short4v p;
            p[0] = (short)f2bf(st[mt][0]); p[1] = (short)f2bf(st[mt][1]);
            p[2] = (short)f2bf(st[mt][2]); p[3] = (short)f2bf(st[mt][3]);
            *(short4v*)&Pt[(w * 16 + l16) * PADP + mt * 16 + quad * 4] = p;
        }

        // ---- O^T += V^T . P^T ----
        bf16x8 pf0 = *(const bf16x8*)&Pt[(w * 16 + l16) * PADP + quad * 8];
        bf16x8 pf1 = *(const bf16x8*)&Pt[(w * 16 + l16) * PADP + 32 + quad * 8];
        __builtin_amdgcn_s_setprio(1);
#pragma unroll
        for (int mt = 0; mt < 8; ++mt) {
            bf16x8 vf0 = *(const bf16x8*)&Vt[(mt * 16 + l16) * PADV + quad * 8];
            bf16x8 vf1 = *(const bf16x8*)&Vt[(mt * 16 + l16) * PADV + 32 + quad * 8];
            O[mt] = __builtin_amdgcn_mfma_f32_16x16x32_bf16(vf0, pf0, O[mt], 0, 0, 0);
            O[mt] = __builtin_amdgcn_mfma_f32_16x16x32_bf16(vf1, pf1, O[mt], 0, 0, 0);
        }
        __builtin_amdgcn_s_setprio(0);
    }

    // ---- partial epilogue: unnormalized O (bf16) + m,l (log2 domain) ----
    const int r = w * 16 + l16;
    const size_t jobbase = (size_t)b * NJOBS + jj;
    unsigned short* po = Opart + jobbase * (128 * 128) + (size_t)r * 128;
#pragma unroll
    for (int mt = 0; mt < 8; ++mt) {
        short4v p;
        p[0] = (short)f2bf(O[mt][0]); p[1] = (short)f2bf(O[mt][1]);
        p[2] = (short)f2bf(O[mt][2]); p[3] = (short)f2bf(O[mt][3]);
        *(short4v*)&po[mt * 16 + quad * 4] = p;
    }
    if (quad == 0) {
        mbuf[jobbase * 128 + r] = m_run;
        lbuf[jobbase * 128 + r] = l_run;
    }
}

// ---------------- Combine partials (log2-domain m) ----------------
// grid (32, 4) x 512 thr: thread -> q-row t>>2 (0..127), 32 head cols at (t&3)*32.
__global__ __launch_bounds__(512) void combine_kernel(
    const unsigned short* __restrict__ Opart, const float* __restrict__ mbuf,
    const float* __restrict__ lbuf, float* __restrict__ out)
{
    const int qi = blockIdx.x, b = blockIdx.y;
    const int nc = (qi + 5) / 5;
    int j0 = 0;
    for (int q = 0; q < qi; ++q) j0 += (q + 5) / 5;
    const int t = threadIdx.x;
    const int row = t >> 2, cg = (t & 3) * 32;

    float mv[MAXC], lv[MAXC];
    float M = -1e30f;
#pragma unroll
    for (int c2 = 0; c2 < MAXC; ++c2) {
        if (c2 < nc) {
            const size_t jb = (size_t)b * NJOBS + j0 + c2;
            mv[c2] = mbuf[jb * 128 + row];
            lv[c2] = lbuf[jb * 128 + row];
            M = fmaxf(M, mv[c2]);
        } else { mv[c2] = -1e30f; lv[c2] = 0.f; }
    }
    float L = 0.f;
#pragma unroll
    for (int c2 = 0; c2 < MAXC; ++c2)
        if (c2 < nc) L += exp2f(mv[c2] - M) * lv[c2];
    const float Linv = 1.0f / L;

    float acc[32];
#pragma unroll
    for (int i = 0; i < 32; ++i) acc[i] = 0.f;
#pragma unroll
    for (int c2 = 0; c2 < MAXC; ++c2) {
        if (c2 < nc) {
            const float wgt = exp2f(mv[c2] - M) * Linv;
            const unsigned short* po = Opart + ((size_t)b * NJOBS + j0 + c2) * (128 * 128) +
                                       (size_t)row * 128 + cg;
#pragma unroll
            for (int i = 0; i < 4; ++i) {
                i32x4 d = *(const i32x4*)&po[i * 8];
#pragma unroll
                for (int e = 0; e < 4; ++e) {
                    unsigned int u = (unsigned int)d[e];
                    acc[i * 8 + e * 2]     = fmaf(wgt, bf2f((unsigned short)(u & 0xffff)), acc[i * 8 + e * 2]);
                    acc[i * 8 + e * 2 + 1] = fmaf(wgt, bf2f((unsigned short)(u >> 16)),   acc[i * 8 + e * 2 + 1]);
                }
            }
        }
    }
    float* op = out + ((size_t)b * SEQ + qi * 128 + row) * HD + cg;
#pragma unroll
    for (int i = 0; i < 8; ++i) {
        float4 res;
        res.x = acc[i * 4]; res.y = acc[i * 4 + 1];
        res.z = acc[i * 4 + 2]; res.w = acc[i * 4 + 3];
        *(float4*)&op[i * 4] = res;
    }
}

extern "C" void kernel_launch(void* const* d_in, const int* in_sizes, int n_in,
                              void* d_out, int out_size, void* d_ws, size_t ws_size,
                              hipStream_t stream) {
    const float* x  = (const float*)d_in[0];
    const float* Wq = (const float*)d_in[1];
    const float* Wk = (const float*)d_in[2];
    const float* Wv = (const float*)d_in[3];

    unsigned short* qb    = (unsigned short*)d_ws;          // [16384][128] bf16
    unsigned short* kb    = qb  + (size_t)MROWS * HD;       // [16384][128] bf16
    unsigned short* vtb   = kb  + (size_t)MROWS * HD;       // [4][128][4096] bf16
    unsigned short* Wt    = vtb + (size_t)MROWS * HD;       // [3][128][1024] bf16
    unsigned short* Opart = Wt  + (size_t)3 * HD * EMB;     // [4][119][128][128] bf16
    float* mbuf = (float*)(Opart + (size_t)BATCH * NJOBS * 128 * 128);
    float* lbuf = mbuf + (size_t)BATCH * NJOBS * 128;
    float* out = (float*)d_out;

    wtrans_kernel <<<dim3(64, 3),  dim3(256), 0, stream>>>(Wq, Wk, Wv, Wt);
    qkv_kernel    <<<dim3(512),    dim3(512), 0, stream>>>(x, Wt, qb, kb, vtb);
    flash_kernel  <<<dim3(480),    dim3(512), 0, stream>>>(qb, kb, vtb, Opart, mbuf, lbuf);
    combine_kernel<<<dim3(32, 4),  dim3(512), 0, stream>>>(Opart, mbuf, lbuf, out);
}

// Round 3
// 187.816 us; speedup vs baseline: 1.0148x; 1.0012x over previous
//
#include <hip/hip_runtime.h>
#include <math.h>

#define BATCH 4
#define SEQ   4096
#define EMB   1024
#define HD    128
#define MROWS (BATCH*SEQ)
#define SCALE  0.08838834764831844f   // 1/sqrt(128)
#define SCALEQ 0.12751742f            // (1/sqrt(128)) * log2(e)  -> exp2-domain scores
#define CHUNK 10                      // kv-tiles (of 64) per split-KV job
#define NJOBS 119                     // jobs per batch at BQ=128, CHUNK=10
#define MAXC  7                       // max chunks per q-tile = ceil(64/10)

typedef __attribute__((ext_vector_type(8))) short bf16x8;   // MFMA A/B frag (4 VGPR)
typedef __attribute__((ext_vector_type(4))) short short4v;  // 8B LDS store
typedef __attribute__((ext_vector_type(4))) float f32x4;    // MFMA C/D frag
typedef __attribute__((ext_vector_type(4))) int   i32x4;    // 16B copy

static __device__ __forceinline__ unsigned short f2bf(float f) {
    unsigned int u = __float_as_uint(f);
    u += 0x7fff + ((u >> 16) & 1);       // RNE
    return (unsigned short)(u >> 16);
}
static __device__ __forceinline__ float bf2f(unsigned short s) {
    return __uint_as_float((unsigned int)s << 16);
}
static __device__ __forceinline__ short4v pack4(float4 a) {
    short4v p;
    p[0] = (short)f2bf(a.x); p[1] = (short)f2bf(a.y);
    p[2] = (short)f2bf(a.z); p[3] = (short)f2bf(a.w);
    return p;
}

// ---------------- W transpose + bf16 (+ fold q-scale * log2e) ----------------
// grid (64, 3) x 256 thr. Block: 16 k-rows x 128 n of one matrix, via LDS transpose.
__global__ __launch_bounds__(256) void wtrans_kernel(
    const float* __restrict__ Wq, const float* __restrict__ Wk,
    const float* __restrict__ Wv, unsigned short* __restrict__ Wt)
{
    __shared__ __align__(16) unsigned short Xs[16 * 132];
    const int w  = blockIdx.y;
    const float* W = (w == 0) ? Wq : (w == 1) ? Wk : Wv;
    const float sc = (w == 0) ? SCALEQ : 1.0f;   // exp2-domain: scores carry log2(e)
    unsigned short* dst = Wt + (size_t)w * 131072;
    const int k0 = blockIdx.x * 16;
    const int t  = threadIdx.x;

#pragma unroll
    for (int i = 0; i < 2; ++i) {
        int gg = i * 256 + t;                 // 0..511
        int row = gg >> 5, c4 = gg & 31;
        float4 a = *(const float4*)&W[(size_t)(k0 + row) * HD + c4 * 4];
        short4v p;
        p[0] = (short)f2bf(a.x * sc); p[1] = (short)f2bf(a.y * sc);
        p[2] = (short)f2bf(a.z * sc); p[3] = (short)f2bf(a.w * sc);
        *(short4v*)&Xs[row * 132 + c4 * 4] = p;
    }
    __syncthreads();
    const int n = t >> 1, half = t & 1;
    i32x4 o;
#pragma unroll
    for (int e = 0; e < 4; ++e) {
        unsigned int lo = Xs[(half * 8 + e * 2    ) * 132 + n];
        unsigned int hi = Xs[(half * 8 + e * 2 + 1) * 132 + n];
        o[e] = (int)(lo | (hi << 16));
    }
    *(i32x4*)&dst[(size_t)n * 1024 + k0 + half * 8] = o;
}

// ---------------- Fused QKV: write-late x staging + raw barriers (no vmcnt drain) ----------------
// grid 512 x 512 thr (8 waves). Wave ng owns n-tiles 3ng..3ng+2 (48 W rows).
// Round-2 failure analysis: (a) x value was loaded AND ds_written in the same phase
// -> full HBM latency exposed at the pack's vmcnt wait every phase; (b) __syncthreads
// compiles to s_waitcnt vmcnt(0) lgkmcnt(0) + s_barrier -> force-drained all W/x
// prefetch loads each phase (VGPR=56 proved buffers weren't even kept live).
// Fix: T14 write-late (ds_write uses x loaded one full phase earlier) + T4 raw
// s_barrier with only lgkmcnt(0) (LDS visibility) -> VMEM prefetches span barriers.
// The asm "memory" clobber pins load issue points so aB0/aB1 stay live.
__global__ __launch_bounds__(512, 4) void qkv_kernel(
    const float* __restrict__ x, const unsigned short* __restrict__ Wt,
    unsigned short* __restrict__ qb, unsigned short* __restrict__ kb,
    unsigned short* __restrict__ vtb)
{
    __shared__ __align__(16) unsigned short lds[13824];  // max(x dbuf 4608, epilogue 13824)
    unsigned short* xs0 = lds;           // x tile 32 x 64, pad 72 (buf 0)
    unsigned short* xs1 = lds + 2304;    // buf 1

    const int t    = threadIdx.x;
    const int lane = t & 63, ng = t >> 6;
    const int quad = lane >> 4, l16 = lane & 15;
    const int m0   = blockIdx.x * 32;

    f32x4 acc[2][3];
#pragma unroll
    for (int i = 0; i < 2; ++i)
#pragma unroll
        for (int j = 0; j < 3; ++j) acc[i][j] = (f32x4){0.f, 0.f, 0.f, 0.f};

    const int xrow = t >> 4, xseg = t & 15;   // all 512 threads stage 4 floats each
    const float* xbase = x + (size_t)(m0 + xrow) * EMB + xseg * 4;
    // per-lane W base: row = ng*48 + jt*16 + l16, col chunk quad*8
    const unsigned short* Wb = Wt + ((size_t)(ng * 48 + l16)) * 1024 + quad * 8;

    bf16x8 aB0[2][3], aB1[2][3];
    float4 xr;

    // prologue: stage x(0) into xs0; load W(0) frags; issue x(64) into xr
    {
        float4 a = *(const float4*)&xbase[0];
#pragma unroll
        for (int ks = 0; ks < 2; ++ks)
#pragma unroll
            for (int jt = 0; jt < 3; ++jt)
                aB0[ks][jt] = *(const bf16x8*)&Wb[(size_t)jt * 16384 + ks * 32];
        *(short4v*)&xs0[xrow * 72 + xseg * 4] = pack4(a);   // waits x(0) only; W stays in flight
        xr = *(const float4*)&xbase[64];                     // issue x(64), lands next phase
    }
    asm volatile("s_waitcnt lgkmcnt(0)" ::: "memory");
    __builtin_amdgcn_s_barrier();

    for (int kt = 0; kt < EMB; kt += 128) {
        // ---- phase A: compute kt (xs0, aB0); stage x(kt+64)->xs1 (write-late);
        //      prefetch xr=x(kt+128), aB1=W(kt+64) ----
        *(short4v*)&xs1[xrow * 72 + xseg * 4] = pack4(xr);   // xr issued one phase ago
        if (kt + 128 < EMB)
            xr = *(const float4*)&xbase[kt + 128];
#pragma unroll
        for (int ks = 0; ks < 2; ++ks)
#pragma unroll
            for (int jt = 0; jt < 3; ++jt)
                aB1[ks][jt] = *(const bf16x8*)&Wb[(size_t)jt * 16384 + kt + 64 + ks * 32];
        {
            bf16x8 aA[2][2];
#pragma unroll
            for (int ks = 0; ks < 2; ++ks)
#pragma unroll
                for (int mt = 0; mt < 2; ++mt)
                    aA[ks][mt] = *(const bf16x8*)&xs0[(mt * 16 + l16) * 72 + ks * 32 + quad * 8];
            __builtin_amdgcn_s_setprio(1);
#pragma unroll
            for (int ks = 0; ks < 2; ++ks)
#pragma unroll
                for (int mt = 0; mt < 2; ++mt)
#pragma unroll
                    for (int jt = 0; jt < 3; ++jt)
                        acc[mt][jt] = __builtin_amdgcn_mfma_f32_16x16x32_bf16(
                            aA[ks][mt], aB0[ks][jt], acc[mt][jt], 0, 0, 0);
            __builtin_amdgcn_s_setprio(0);
        }
        asm volatile("s_waitcnt lgkmcnt(0)" ::: "memory");   // ds_write visible + ds_reads done
        __builtin_amdgcn_s_barrier();                        // NO vmcnt drain: prefetch in flight

        // ---- phase B: compute kt+64 (xs1, aB1); stage x(kt+128)->xs0;
        //      prefetch xr=x(kt+192), aB0=W(kt+128) ----
        if (kt + 128 < EMB) {
            *(short4v*)&xs0[xrow * 72 + xseg * 4] = pack4(xr);
            if (kt + 192 < EMB)
                xr = *(const float4*)&xbase[kt + 192];
#pragma unroll
            for (int ks = 0; ks < 2; ++ks)
#pragma unroll
                for (int jt = 0; jt < 3; ++jt)
                    aB0[ks][jt] = *(const bf16x8*)&Wb[(size_t)jt * 16384 + kt + 128 + ks * 32];
        }
        {
            bf16x8 aA[2][2];
#pragma unroll
            for (int ks = 0; ks < 2; ++ks)
#pragma unroll
                for (int mt = 0; mt < 2; ++mt)
                    aA[ks][mt] = *(const bf16x8*)&xs1[(mt * 16 + l16) * 72 + ks * 32 + quad * 8];
            __builtin_amdgcn_s_setprio(1);
#pragma unroll
            for (int ks = 0; ks < 2; ++ks)
#pragma unroll
                for (int mt = 0; mt < 2; ++mt)
#pragma unroll
                    for (int jt = 0; jt < 3; ++jt)
                        acc[mt][jt] = __builtin_amdgcn_mfma_f32_16x16x32_bf16(
                            aA[ks][mt], aB1[ks][jt], acc[mt][jt], 0, 0, 0);
            __builtin_amdgcn_s_setprio(0);
        }
        asm volatile("s_waitcnt lgkmcnt(0)" ::: "memory");
        __builtin_amdgcn_s_barrier();
    }

    // ---- epilogue: scatter to LDS (per-matrix layout), then coalesced copy out ----
    unsigned short* Cq = lds;                 // [32][136]
    unsigned short* Ck = lds + 32 * 136;      // [32][136]
    unsigned short* Cv = lds + 2 * 32 * 136;  // [128][40] transposed
#pragma unroll
    for (int mt = 0; mt < 2; ++mt)
#pragma unroll
        for (int jt = 0; jt < 3; ++jt) {
            int nt = ng * 3 + jt;
            int wm = nt >> 3, nl = nt & 7;
            if (wm < 2) {
                unsigned short* C = (wm == 0) ? Cq : Ck;
#pragma unroll
                for (int rr = 0; rr < 4; ++rr)
                    C[(mt * 16 + quad * 4 + rr) * 136 + nl * 16 + l16] =
                        f2bf(acc[mt][jt][rr]);
            } else {
                short4v p;
                p[0] = (short)f2bf(acc[mt][jt][0]); p[1] = (short)f2bf(acc[mt][jt][1]);
                p[2] = (short)f2bf(acc[mt][jt][2]); p[3] = (short)f2bf(acc[mt][jt][3]);
                *(short4v*)&Cv[(nl * 16 + l16) * 40 + mt * 16 + quad * 4] = p;
            }
        }
    __syncthreads();
    {   // q, k: 32 x 128 each -> 512 i32x4, one per thread
        int row = t >> 4, seg = t & 15;
        *(i32x4*)&qb[((size_t)(m0 + row)) * HD + seg * 8] = *(const i32x4*)&Cq[row * 136 + seg * 8];
        *(i32x4*)&kb[((size_t)(m0 + row)) * HD + seg * 8] = *(const i32x4*)&Ck[row * 136 + seg * 8];
    }
    {   // v^T: 128 x 32 -> 512 i32x4, one per thread
        const int b = m0 >> 12, s0 = m0 & 4095;
        int h = t >> 2, seg = t & 3;
        *(i32x4*)&vtb[(size_t)b * (HD * SEQ) + (size_t)h * SEQ + s0 + seg * 8] =
            *(const i32x4*)&Cv[h * 40 + seg * 8];
    }
}

// ---------------- Flash attention: split-KV, BQ=128, 8 waves, XCD-batch affinity ----------------
// grid 480 x 512 thr. bx -> slot=bx&7 (≈XCD), batch=slot>>1, jj=(bx>>3)*2+(slot&1).
// Each XCD sees one batch -> K/V (4 MB) stays L2-resident.
// T14 async-stage: next tile's K/V loaded into regs before compute, written after barrier.
// exp2-domain online softmax (scores pre-scaled by log2e via Wq) + T13 defer-max.
#define PADK 136
#define PADV 72
#define PADP 72
#define DEFER_THR 8.0f   // log2 domain: P bounded by 2^8=256, safe in bf16/f32

__global__ __launch_bounds__(512, 4) void flash_kernel(
    const unsigned short* __restrict__ qb, const unsigned short* __restrict__ kb,
    const unsigned short* __restrict__ vtb, unsigned short* __restrict__ Opart,
    float* __restrict__ mbuf, float* __restrict__ lbuf)
{
    __shared__ __align__(16) unsigned short Ks[64 * PADK];    // 17.4 KB
    __shared__ __align__(16) unsigned short Vt[128 * PADV];   // 18.4 KB
    __shared__ __align__(16) unsigned short Pt[128 * PADP];   // 18.4 KB

    const int bx   = blockIdx.x;
    const int slot = bx & 7, pp = bx >> 3;
    const int b    = slot >> 1;
    const int jj   = pp * 2 + (slot & 1);
    if (jj >= NJOBS) return;                 // dummy pad blocks (no barrier yet)

    const int t    = threadIdx.x;
    const int lane = t & 63, w = t >> 6;     // 8 waves
    const int quad = lane >> 4, l16 = lane & 15;

    // decode jj -> (qi, c): q-tile qi has ceil((qi+1)/5) chunks
    int qi = 0, s = 0;
    for (qi = 0; qi < 32; ++qi) {
        int cnt = (qi + 5) / 5;
        if (jj < s + cnt) break;
        s += cnt;
    }
    const int c    = jj - s;
    const int qrow = qi * 128 + w * 16 + l16;
    const int jmax = 2 * qi + 2;
    const int jbeg = c * CHUNK;
    const int jend = min(jbeg + CHUNK, jmax);
    const int wtop = qi * 128 + w * 16;      // wave's lowest q-row

    bf16x8 qf[4];
    {
        const unsigned short* qp = qb + ((size_t)b * SEQ + qrow) * HD;
#pragma unroll
        for (int ks = 0; ks < 4; ++ks)
            qf[ks] = *(const bf16x8*)&qp[ks * 32 + quad * 8];
    }

    f32x4 O[8];
#pragma unroll
    for (int i = 0; i < 8; ++i) O[i] = (f32x4){0.f, 0.f, 0.f, 0.f};
    float m_run = -1e30f, l_run = 0.f;

    const unsigned short* kbb  = kb  + (size_t)b * SEQ * HD;
    const unsigned short* vtbb = vtb + (size_t)b * HD * SEQ;

    const int gg0 = t, gg1 = 512 + t;
    // prologue: load first tile into regs
    i32x4 kr0, kr1, vr0, vr1;
    kr0 = *(const i32x4*)&kbb[(size_t)jbeg * 64 * HD + (size_t)gg0 * 8];
    kr1 = *(const i32x4*)&kbb[(size_t)jbeg * 64 * HD + (size_t)gg1 * 8];
    vr0 = *(const i32x4*)&vtbb[(size_t)(gg0 >> 3) * SEQ + jbeg * 64 + (gg0 & 7) * 8];
    vr1 = *(const i32x4*)&vtbb[(size_t)(gg1 >> 3) * SEQ + jbeg * 64 + (gg1 & 7) * 8];

    for (int j0 = jbeg; j0 < jend; ++j0) {
        __syncthreads();   // prior iteration's reads of Ks/Vt complete (WAR)
        // write prefetched tile (vmcnt drained here, hidden under prior compute)
        *(i32x4*)&Ks[(gg0 >> 4) * PADK + (gg0 & 15) * 8] = kr0;
        *(i32x4*)&Ks[(gg1 >> 4) * PADK + (gg1 & 15) * 8] = kr1;
        *(i32x4*)&Vt[(gg0 >> 3) * PADV + (gg0 & 7) * 8] = vr0;
        *(i32x4*)&Vt[(gg1 >> 3) * PADV + (gg1 & 7) * 8] = vr1;
        __syncthreads();

        // issue next tile's loads NOW — latency hides under this tile's compute
        if (j0 + 1 < jend) {
            const int j1 = j0 + 1;
            kr0 = *(const i32x4*)&kbb[(size_t)j1 * 64 * HD + (size_t)gg0 * 8];
            kr1 = *(const i32x4*)&kbb[(size_t)j1 * 64 * HD + (size_t)gg1 * 8];
            vr0 = *(const i32x4*)&vtbb[(size_t)(gg0 >> 3) * SEQ + j1 * 64 + (gg0 & 7) * 8];
            vr1 = *(const i32x4*)&vtbb[(size_t)(gg1 >> 3) * SEQ + j1 * 64 + (gg1 & 7) * 8];
        }

        // fully-masked tile for this wave? -> skip compute (loads already issued)
        if (j0 * 64 > wtop + 15) continue;

        // ---- S^T = K . Q^T ----
        f32x4 st[4];
        __builtin_amdgcn_s_setprio(1);
#pragma unroll
        for (int mt = 0; mt < 4; ++mt) {
            f32x4 a = (f32x4){0.f, 0.f, 0.f, 0.f};
#pragma unroll
            for (int ks = 0; ks < 4; ++ks) {
                bf16x8 kf = *(const bf16x8*)&Ks[(mt * 16 + l16) * PADK + ks * 32 + quad * 8];
                a = __builtin_amdgcn_mfma_f32_16x16x32_bf16(kf, qf[ks], a, 0, 0, 0);
            }
            st[mt] = a;
        }
        __builtin_amdgcn_s_setprio(0);

        // ---- causal mask (skip when tile fully valid for this wave) ----
        if (j0 * 64 + 63 > wtop) {
#pragma unroll
            for (int mt = 0; mt < 4; ++mt)
#pragma unroll
                for (int rr = 0; rr < 4; ++rr) {
                    int kv = j0 * 64 + mt * 16 + quad * 4 + rr;
                    if (kv > qrow) st[mt][rr] = -1e30f;
                }
        }
        // NOTE: rows with zero valid entries yield m=-1e30 garbage partials;
        // combine neutralizes them via wgt = exp2(-1e30 - M) = 0.

        // ---- online softmax, exp2 domain (lane owns one q-row) ----
        float mx = -1e30f;
#pragma unroll
        for (int mt = 0; mt < 4; ++mt)
#pragma unroll
            for (int rr = 0; rr < 4; ++rr) mx = fmaxf(mx, st[mt][rr]);
        mx = fmaxf(mx, __shfl_xor(mx, 16));
        mx = fmaxf(mx, __shfl_xor(mx, 32));
        // T13 defer-max: only rescale when the wave's max grew past THR
        if (!__all(mx <= m_run + DEFER_THR)) {
            const float m_new = fmaxf(m_run, mx);
            const float alpha = exp2f(m_run - m_new);
            l_run *= alpha;
#pragma unroll
            for (int i = 0; i < 8; ++i) {
                O[i][0] *= alpha; O[i][1] *= alpha; O[i][2] *= alpha; O[i][3] *= alpha;
            }
            m_run = m_new;
        }
        float psum = 0.f;
#pragma unroll
        for (int mt = 0; mt < 4; ++mt)
#pragma unroll
            for (int rr = 0; rr < 4; ++rr) {
                float p = exp2f(st[mt][rr] - m_run);
                st[mt][rr] = p;
                psum += p;
            }
        psum += __shfl_xor(psum, 16);
        psum += __shfl_xor(psum, 32);
        l_run += psum;

        // ---- P^T -> LDS (wave-private rows; no barrier needed) ----
#pragma unroll
        for (int mt = 0; mt < 4; ++mt) {
            short4v p;
            p[0] = (short)f2bf(st[mt][0]); p[1] = (short)f2bf(st[mt][1]);
            p[2] = (short)f2bf(st[mt][2]); p[3] = (short)f2bf(st[mt][3]);
            *(short4v*)&Pt[(w * 16 + l16) * PADP + mt * 16 + quad * 4] = p;
        }

        // ---- O^T += V^T . P^T ----
        bf16x8 pf0 = *(const bf16x8*)&Pt[(w * 16 + l16) * PADP + quad * 8];
        bf16x8 pf1 = *(const bf16x8*)&Pt[(w * 16 + l16) * PADP + 32 + quad * 8];
        __builtin_amdgcn_s_setprio(1);
#pragma unroll
        for (int mt = 0; mt < 8; ++mt) {
            bf16x8 vf0 = *(const bf16x8*)&Vt[(mt * 16 + l16) * PADV + quad * 8];
            bf16x8 vf1 = *(const bf16x8*)&Vt[(mt * 16 + l16) * PADV + 32 + quad * 8];
            O[mt] = __builtin_amdgcn_mfma_f32_16x16x32_bf16(vf0, pf0, O[mt], 0, 0, 0);
            O[mt] = __builtin_amdgcn_mfma_f32_16x16x32_bf16(vf1, pf1, O[mt], 0, 0, 0);
        }
        __builtin_amdgcn_s_setprio(0);
    }

    // ---- partial epilogue: unnormalized O (bf16) + m,l (log2 domain) ----
    const int r = w * 16 + l16;
    const size_t jobbase = (size_t)b * NJOBS + jj;
    unsigned short* po = Opart + jobbase * (128 * 128) + (size_t)r * 128;
#pragma unroll
    for (int mt = 0; mt < 8; ++mt) {
        short4v p;
        p[0] = (short)f2bf(O[mt][0]); p[1] = (short)f2bf(O[mt][1]);
        p[2] = (short)f2bf(O[mt][2]); p[3] = (short)f2bf(O[mt][3]);
        *(short4v*)&po[mt * 16 + quad * 4] = p;
    }
    if (quad == 0) {
        mbuf[jobbase * 128 + r] = m_run;
        lbuf[jobbase * 128 + r] = l_run;
    }
}

// ---------------- Combine partials (log2-domain m) ----------------
// grid (32, 4) x 512 thr: thread -> q-row t>>2 (0..127), 32 head cols at (t&3)*32.
__global__ __launch_bounds__(512) void combine_kernel(
    const unsigned short* __restrict__ Opart, const float* __restrict__ mbuf,
    const float* __restrict__ lbuf, float* __restrict__ out)
{
    const int qi = blockIdx.x, b = blockIdx.y;
    const int nc = (qi + 5) / 5;
    int j0 = 0;
    for (int q = 0; q < qi; ++q) j0 += (q + 5) / 5;
    const int t = threadIdx.x;
    const int row = t >> 2, cg = (t & 3) * 32;

    float mv[MAXC], lv[MAXC];
    float M = -1e30f;
#pragma unroll
    for (int c2 = 0; c2 < MAXC; ++c2) {
        if (c2 < nc) {
            const size_t jb = (size_t)b * NJOBS + j0 + c2;
            mv[c2] = mbuf[jb * 128 + row];
            lv[c2] = lbuf[jb * 128 + row];
            M = fmaxf(M, mv[c2]);
        } else { mv[c2] = -1e30f; lv[c2] = 0.f; }
    }
    float L = 0.f;
#pragma unroll
    for (int c2 = 0; c2 < MAXC; ++c2)
        if (c2 < nc) L += exp2f(mv[c2] - M) * lv[c2];
    const float Linv = 1.0f / L;

    float acc[32];
#pragma unroll
    for (int i = 0; i < 32; ++i) acc[i] = 0.f;
#pragma unroll
    for (int c2 = 0; c2 < MAXC; ++c2) {
        if (c2 < nc) {
            const float wgt = exp2f(mv[c2] - M) * Linv;
            const unsigned short* po = Opart + ((size_t)b * NJOBS + j0 + c2) * (128 * 128) +
                                       (size_t)row * 128 + cg;
#pragma unroll
            for (int i = 0; i < 4; ++i) {
                i32x4 d = *(const i32x4*)&po[i * 8];
#pragma unroll
                for (int e = 0; e < 4; ++e) {
                    unsigned int u = (unsigned int)d[e];
                    acc[i * 8 + e * 2]     = fmaf(wgt, bf2f((unsigned short)(u & 0xffff)), acc[i * 8 + e * 2]);
                    acc[i * 8 + e * 2 + 1] = fmaf(wgt, bf2f((unsigned short)(u >> 16)),   acc[i * 8 + e * 2 + 1]);
                }
            }
        }
    }
    float* op = out + ((size_t)b * SEQ + qi * 128 + row) * HD + cg;
#pragma unroll
    for (int i = 0; i < 8; ++i) {
        float4 res;
        res.x = acc[i * 4]; res.y = acc[i * 4 + 1];
        res.z = acc[i * 4 + 2]; res.w = acc[i * 4 + 3];
        *(float4*)&op[i * 4] = res;
    }
}

extern "C" void kernel_launch(void* const* d_in, const int* in_sizes, int n_in,
                              void* d_out, int out_size, void* d_ws, size_t ws_size,
                              hipStream_t stream) {
    const float* x  = (const float*)d_in[0];
    const float* Wq = (const float*)d_in[1];
    const float* Wk = (const float*)d_in[2];
    const float* Wv = (const float*)d_in[3];

    unsigned short* qb    = (unsigned short*)d_ws;          // [16384][128] bf16
    unsigned short* kb    = qb  + (size_t)MROWS * HD;       // [16384][128] bf16
    unsigned short* vtb   = kb  + (size_t)MROWS * HD;       // [4][128][4096] bf16
    unsigned short* Wt    = vtb + (size_t)MROWS * HD;       // [3][128][1024] bf16
    unsigned short* Opart = Wt  + (size_t)3 * HD * EMB;     // [4][119][128][128] bf16
    float* mbuf = (float*)(Opart + (size_t)BATCH * NJOBS * 128 * 128);
    float* lbuf = mbuf + (size_t)BATCH * NJOBS * 128;
    float* out = (float*)d_out;

    wtrans_kernel <<<dim3(64, 3),  dim3(256), 0, stream>>>(Wq, Wk, Wv, Wt);
    qkv_kernel    <<<dim3(512),    dim3(512), 0, stream>>>(x, Wt, qb, kb, vtb);
    flash_kernel  <<<dim3(480),    dim3(512), 0, stream>>>(qb, kb, vtb, Opart, mbuf, lbuf);
    combine_kernel<<<dim3(32, 4),  dim3(512), 0, stream>>>(Opart, mbuf, lbuf, out);
}

// Round 4
// 171.525 us; speedup vs baseline: 1.1112x; 1.0950x over previous
//
#include <hip/hip_runtime.h>
#include <math.h>

#define BATCH 4
#define SEQ   4096
#define EMB   1024
#define HD    128
#define MROWS (BATCH*SEQ)
#define SCALE  0.08838834764831844f   // 1/sqrt(128)
#define SCALEQ 0.12751742f            // (1/sqrt(128)) * log2(e)  -> exp2-domain scores
#define CHUNK 10                      // kv-tiles (of 64) per split-KV job
#define NJOBS 119                     // jobs per batch at BQ=128, CHUNK=10
#define MAXC  7                       // max chunks per q-tile = ceil(64/10)

typedef __attribute__((ext_vector_type(8))) short bf16x8;   // MFMA A/B frag (4 VGPR)
typedef __attribute__((ext_vector_type(4))) short short4v;  // 8B LDS store
typedef __attribute__((ext_vector_type(4))) float f32x4;    // MFMA C/D frag
typedef __attribute__((ext_vector_type(4))) int   i32x4;    // 16B copy

static __device__ __forceinline__ unsigned short f2bf(float f) {
    unsigned int u = __float_as_uint(f);
    u += 0x7fff + ((u >> 16) & 1);       // RNE
    return (unsigned short)(u >> 16);
}
static __device__ __forceinline__ float bf2f(unsigned short s) {
    return __uint_as_float((unsigned int)s << 16);
}
static __device__ __forceinline__ short4v pack4(float4 a) {
    short4v p;
    p[0] = (short)f2bf(a.x); p[1] = (short)f2bf(a.y);
    p[2] = (short)f2bf(a.z); p[3] = (short)f2bf(a.w);
    return p;
}

// ---------------- W transpose + bf16 -> FRAGMENT-CONTIGUOUS layout ----------------
// Wfrag[ntg][kc][lane] of 16B, ntg = (w*128+n)>>4 (24 tiles), kc = k>>5 (32 chunks),
// lane = quad*16 + (n&15), quad = (k>>3)&3, element e = k&7.
// A wave's MFMA B-frag load for (ntg,kc) is then ONE contiguous 1KB read (lane*16B).
// Round-3 failure: n-major Wt made frag loads 16 rows x 64B at 2KB stride -> 2x L2
// amplification + 16 line-transactions/instr; qkv was W-L2-traffic-bound at 57us.
__global__ __launch_bounds__(256) void wtrans_kernel(
    const float* __restrict__ Wq, const float* __restrict__ Wk,
    const float* __restrict__ Wv, unsigned short* __restrict__ Wt)
{
    __shared__ __align__(16) unsigned short Xs[16 * 132];
    const int w  = blockIdx.y;
    const float* W = (w == 0) ? Wq : (w == 1) ? Wk : Wv;
    const float sc = (w == 0) ? SCALEQ : 1.0f;   // exp2-domain: scores carry log2(e)
    const int bx = blockIdx.x;
    const int k0 = bx * 16;
    const int t  = threadIdx.x;

#pragma unroll
    for (int i = 0; i < 2; ++i) {
        int gg = i * 256 + t;                 // 0..511
        int row = gg >> 5, c4 = gg & 31;      // row = k-row in tile, c4*4 = n
        float4 a = *(const float4*)&W[(size_t)(k0 + row) * HD + c4 * 4];
        short4v p;
        p[0] = (short)f2bf(a.x * sc); p[1] = (short)f2bf(a.y * sc);
        p[2] = (short)f2bf(a.z * sc); p[3] = (short)f2bf(a.w * sc);
        *(short4v*)&Xs[row * 132 + c4 * 4] = p;
    }
    __syncthreads();
    // thread -> (n, g): 8 consecutive k = k0 + g*8 + 0..7 of column n
    const int n = t >> 1, g = t & 1;
    i32x4 o;
#pragma unroll
    for (int e = 0; e < 4; ++e) {
        unsigned int lo = Xs[(g * 8 + e * 2    ) * 132 + n];
        unsigned int hi = Xs[(g * 8 + e * 2 + 1) * 132 + n];
        o[e] = (int)(lo | (hi << 16));
    }
    const int ntg  = w * 8 + (n >> 4);
    const int kc   = bx >> 1;
    const int quad = (bx * 2 + g) & 3;
    const int lane = quad * 16 + (n & 15);
    *(i32x4*)&Wt[(((size_t)ntg * 32 + kc) * 64 + lane) * 8] = o;
}

// ---------------- Fused QKV: M=64/block, frag-contiguous W direct-to-reg, dbuf ----------------
// grid 256 x 512 thr (8 waves), 1 block/CU. Wave ng owns n-tiles 3ng..3ng+2 (48 cols),
// all 4 m-tiles (64 rows). W frags: one contiguous 1KB load per (ntg,kc) per wave,
// double-buffered one phase ahead (aB0/aB1). x: fp32->bf16 staged to LDS, write-late
// (T14) with raw lgkmcnt-only barriers (T4) so VMEM prefetches span barriers.
// M=64 halves total W L2 traffic vs M=32 (each block reads the whole 768KB Wt).
__global__ __launch_bounds__(512, 2) void qkv_kernel(
    const float* __restrict__ x, const unsigned short* __restrict__ Wt,
    unsigned short* __restrict__ qb, unsigned short* __restrict__ kb,
    unsigned short* __restrict__ vtb)
{
    __shared__ __align__(16) unsigned short lds[26624];  // max(x dbuf 9216, epilogue 26624)
    unsigned short* xs0 = lds;           // x tile 64 x 64, pad 72 (buf 0)
    unsigned short* xs1 = lds + 4608;    // buf 1

    const int t    = threadIdx.x;
    const int lane = t & 63, ng = t >> 6;
    const int quad = lane >> 4, l16 = lane & 15;
    const int m0   = blockIdx.x * 64;

    f32x4 acc[4][3];
#pragma unroll
    for (int i = 0; i < 4; ++i)
#pragma unroll
        for (int j = 0; j < 3; ++j) acc[i][j] = (f32x4){0.f, 0.f, 0.f, 0.f};

    // x staging: 64 rows x 64 floats per phase = 1024 float4; thread handles idx t, t+512
    const int xr0 = t >> 4,        xs0c = (t & 15) * 4;          // idx t
    const int xr1 = (t + 512) >> 4, xs1c = ((t + 512) & 15) * 4; // idx t+512
    const float* xb0 = x + (size_t)(m0 + xr0) * EMB + xs0c;
    const float* xb1 = x + (size_t)(m0 + xr1) * EMB + xs1c;

    // W frag base: per-lane 16B slot; per (ntg,kc): + ntg*16384 + kc*512 shorts
    const unsigned short* Wl = Wt + (size_t)lane * 8;
    const size_t jb0 = (size_t)(ng * 3 + 0) * 16384;
    const size_t jb1 = (size_t)(ng * 3 + 1) * 16384;
    const size_t jb2 = (size_t)(ng * 3 + 2) * 16384;

    bf16x8 aB0[2][3], aB1[2][3];
    float4 xra, xrb;

    // prologue: stage x(0) -> xs0; load aB0 (kc=0,1); issue x(64) -> xra/xrb
    {
        float4 a = *(const float4*)&xb0[0];
        float4 b = *(const float4*)&xb1[0];
#pragma unroll
        for (int ks = 0; ks < 2; ++ks) {
            aB0[ks][0] = *(const bf16x8*)&Wl[jb0 + (size_t)ks * 512];
            aB0[ks][1] = *(const bf16x8*)&Wl[jb1 + (size_t)ks * 512];
            aB0[ks][2] = *(const bf16x8*)&Wl[jb2 + (size_t)ks * 512];
        }
        *(short4v*)&xs0[xr0 * 72 + xs0c] = pack4(a);   // waits x only; W stays in flight
        *(short4v*)&xs0[xr1 * 72 + xs1c] = pack4(b);
        xra = *(const float4*)&xb0[64];
        xrb = *(const float4*)&xb1[64];
    }
    asm volatile("s_waitcnt lgkmcnt(0)" ::: "memory");
    __builtin_amdgcn_s_barrier();

    for (int kt = 0; kt < EMB; kt += 128) {
        const size_t kcA = (size_t)(kt >> 5);
        // ---- phase A: compute [kt,kt+64) (xs0, aB0); stage x(kt+64)->xs1 (write-late);
        //      prefetch xra/xrb=x(kt+128), aB1=W(kc=kcA+2,+3) ----
        *(short4v*)&xs1[xr0 * 72 + xs0c] = pack4(xra);   // xra issued one phase ago
        *(short4v*)&xs1[xr1 * 72 + xs1c] = pack4(xrb);
        if (kt + 128 < EMB) {
            xra = *(const float4*)&xb0[kt + 128];
            xrb = *(const float4*)&xb1[kt + 128];
        }
#pragma unroll
        for (int ks = 0; ks < 2; ++ks) {
            aB1[ks][0] = *(const bf16x8*)&Wl[jb0 + (kcA + 2 + ks) * 512];
            aB1[ks][1] = *(const bf16x8*)&Wl[jb1 + (kcA + 2 + ks) * 512];
            aB1[ks][2] = *(const bf16x8*)&Wl[jb2 + (kcA + 2 + ks) * 512];
        }
        {
            bf16x8 aA[2][4];
#pragma unroll
            for (int ks = 0; ks < 2; ++ks)
#pragma unroll
                for (int mt = 0; mt < 4; ++mt)
                    aA[ks][mt] = *(const bf16x8*)&xs0[(mt * 16 + l16) * 72 + ks * 32 + quad * 8];
            __builtin_amdgcn_s_setprio(1);
#pragma unroll
            for (int ks = 0; ks < 2; ++ks)
#pragma unroll
                for (int mt = 0; mt < 4; ++mt)
#pragma unroll
                    for (int jt = 0; jt < 3; ++jt)
                        acc[mt][jt] = __builtin_amdgcn_mfma_f32_16x16x32_bf16(
                            aA[ks][mt], aB0[ks][jt], acc[mt][jt], 0, 0, 0);
            __builtin_amdgcn_s_setprio(0);
        }
        asm volatile("s_waitcnt lgkmcnt(0)" ::: "memory");   // ds_write visible + ds_reads done
        __builtin_amdgcn_s_barrier();                        // NO vmcnt drain

        // ---- phase B: compute [kt+64,kt+128) (xs1, aB1); stage x(kt+128)->xs0;
        //      prefetch xra/xrb=x(kt+192), aB0=W(kc=kcA+4,+5) ----
        if (kt + 128 < EMB) {
            *(short4v*)&xs0[xr0 * 72 + xs0c] = pack4(xra);
            *(short4v*)&xs0[xr1 * 72 + xs1c] = pack4(xrb);
            if (kt + 192 < EMB) {
                xra = *(const float4*)&xb0[kt + 192];
                xrb = *(const float4*)&xb1[kt + 192];
            }
#pragma unroll
            for (int ks = 0; ks < 2; ++ks) {
                aB0[ks][0] = *(const bf16x8*)&Wl[jb0 + (kcA + 4 + ks) * 512];
                aB0[ks][1] = *(const bf16x8*)&Wl[jb1 + (kcA + 4 + ks) * 512];
                aB0[ks][2] = *(const bf16x8*)&Wl[jb2 + (kcA + 4 + ks) * 512];
            }
        }
        {
            bf16x8 aA[2][4];
#pragma unroll
            for (int ks = 0; ks < 2; ++ks)
#pragma unroll
                for (int mt = 0; mt < 4; ++mt)
                    aA[ks][mt] = *(const bf16x8*)&xs1[(mt * 16 + l16) * 72 + ks * 32 + quad * 8];
            __builtin_amdgcn_s_setprio(1);
#pragma unroll
            for (int ks = 0; ks < 2; ++ks)
#pragma unroll
                for (int mt = 0; mt < 4; ++mt)
#pragma unroll
                    for (int jt = 0; jt < 3; ++jt)
                        acc[mt][jt] = __builtin_amdgcn_mfma_f32_16x16x32_bf16(
                            aA[ks][mt], aB1[ks][jt], acc[mt][jt], 0, 0, 0);
            __builtin_amdgcn_s_setprio(0);
        }
        asm volatile("s_waitcnt lgkmcnt(0)" ::: "memory");
        __builtin_amdgcn_s_barrier();
    }

    // ---- epilogue: scatter to LDS (per-matrix layout), then coalesced copy out ----
    unsigned short* Cq = lds;                 // [64][136]
    unsigned short* Ck = lds + 64 * 136;      // [64][136]
    unsigned short* Cv = lds + 2 * 64 * 136;  // [128][72] transposed
#pragma unroll
    for (int mt = 0; mt < 4; ++mt)
#pragma unroll
        for (int jt = 0; jt < 3; ++jt) {
            int nt = ng * 3 + jt;
            int wm = nt >> 3, nl = nt & 7;
            if (wm < 2) {
                unsigned short* C = (wm == 0) ? Cq : Ck;
#pragma unroll
                for (int rr = 0; rr < 4; ++rr)
                    C[(mt * 16 + quad * 4 + rr) * 136 + nl * 16 + l16] =
                        f2bf(acc[mt][jt][rr]);
            } else {
                short4v p;
                p[0] = (short)f2bf(acc[mt][jt][0]); p[1] = (short)f2bf(acc[mt][jt][1]);
                p[2] = (short)f2bf(acc[mt][jt][2]); p[3] = (short)f2bf(acc[mt][jt][3]);
                *(short4v*)&Cv[(nl * 16 + l16) * 72 + mt * 16 + quad * 4] = p;
            }
        }
    __syncthreads();
    {   // q, k: 64 x 128 each -> 1024 i32x4; thread handles idx t, t+512
#pragma unroll
        for (int i = 0; i < 2; ++i) {
            int idx = i * 512 + t;
            int row = idx >> 4, seg = idx & 15;
            *(i32x4*)&qb[((size_t)(m0 + row)) * HD + seg * 8] = *(const i32x4*)&Cq[row * 136 + seg * 8];
            *(i32x4*)&kb[((size_t)(m0 + row)) * HD + seg * 8] = *(const i32x4*)&Ck[row * 136 + seg * 8];
        }
    }
    {   // v^T: 128 x 64 -> 1024 i32x4; thread handles idx t, t+512
        const int b = m0 >> 12, s0 = m0 & 4095;
#pragma unroll
        for (int i = 0; i < 2; ++i) {
            int idx = i * 512 + t;
            int h = idx >> 3, seg = idx & 7;
            *(i32x4*)&vtb[(size_t)b * (HD * SEQ) + (size_t)h * SEQ + s0 + seg * 8] =
                *(const i32x4*)&Cv[h * 72 + seg * 8];
        }
    }
}

// ---------------- Flash attention: split-KV, BQ=128, 8 waves, XCD-batch affinity ----------------
// grid 480 x 512 thr. bx -> slot=bx&7 (≈XCD), batch=slot>>1, jj=(bx>>3)*2+(slot&1).
// Each XCD sees one batch -> K/V (4 MB) stays L2-resident.
// T14 async-stage: next tile's K/V loaded into regs before compute, written after barrier.
// exp2-domain online softmax (scores pre-scaled by log2e via Wq) + T13 defer-max.
#define PADK 136
#define PADV 72
#define PADP 72
#define DEFER_THR 8.0f   // log2 domain: P bounded by 2^8=256, safe in bf16/f32

__global__ __launch_bounds__(512, 4) void flash_kernel(
    const unsigned short* __restrict__ qb, const unsigned short* __restrict__ kb,
    const unsigned short* __restrict__ vtb, unsigned short* __restrict__ Opart,
    float* __restrict__ mbuf, float* __restrict__ lbuf)
{
    __shared__ __align__(16) unsigned short Ks[64 * PADK];    // 17.4 KB
    __shared__ __align__(16) unsigned short Vt[128 * PADV];   // 18.4 KB
    __shared__ __align__(16) unsigned short Pt[128 * PADP];   // 18.4 KB

    const int bx   = blockIdx.x;
    const int slot = bx & 7, pp = bx >> 3;
    const int b    = slot >> 1;
    const int jj   = pp * 2 + (slot & 1);
    if (jj >= NJOBS) return;                 // dummy pad blocks (no barrier yet)

    const int t    = threadIdx.x;
    const int lane = t & 63, w = t >> 6;     // 8 waves
    const int quad = lane >> 4, l16 = lane & 15;

    // decode jj -> (qi, c): q-tile qi has ceil((qi+1)/5) chunks
    int qi = 0, s = 0;
    for (qi = 0; qi < 32; ++qi) {
        int cnt = (qi + 5) / 5;
        if (jj < s + cnt) break;
        s += cnt;
    }
    const int c    = jj - s;
    const int qrow = qi * 128 + w * 16 + l16;
    const int jmax = 2 * qi + 2;
    const int jbeg = c * CHUNK;
    const int jend = min(jbeg + CHUNK, jmax);
    const int wtop = qi * 128 + w * 16;      // wave's lowest q-row

    bf16x8 qf[4];
    {
        const unsigned short* qp = qb + ((size_t)b * SEQ + qrow) * HD;
#pragma unroll
        for (int ks = 0; ks < 4; ++ks)
            qf[ks] = *(const bf16x8*)&qp[ks * 32 + quad * 8];
    }

    f32x4 O[8];
#pragma unroll
    for (int i = 0; i < 8; ++i) O[i] = (f32x4){0.f, 0.f, 0.f, 0.f};
    float m_run = -1e30f, l_run = 0.f;

    const unsigned short* kbb  = kb  + (size_t)b * SEQ * HD;
    const unsigned short* vtbb = vtb + (size_t)b * HD * SEQ;

    const int gg0 = t, gg1 = 512 + t;
    // prologue: load first tile into regs
    i32x4 kr0, kr1, vr0, vr1;
    kr0 = *(const i32x4*)&kbb[(size_t)jbeg * 64 * HD + (size_t)gg0 * 8];
    kr1 = *(const i32x4*)&kbb[(size_t)jbeg * 64 * HD + (size_t)gg1 * 8];
    vr0 = *(const i32x4*)&vtbb[(size_t)(gg0 >> 3) * SEQ + jbeg * 64 + (gg0 & 7) * 8];
    vr1 = *(const i32x4*)&vtbb[(size_t)(gg1 >> 3) * SEQ + jbeg * 64 + (gg1 & 7) * 8];

    for (int j0 = jbeg; j0 < jend; ++j0) {
        __syncthreads();   // prior iteration's reads of Ks/Vt complete (WAR)
        // write prefetched tile (vmcnt drained here, hidden under prior compute)
        *(i32x4*)&Ks[(gg0 >> 4) * PADK + (gg0 & 15) * 8] = kr0;
        *(i32x4*)&Ks[(gg1 >> 4) * PADK + (gg1 & 15) * 8] = kr1;
        *(i32x4*)&Vt[(gg0 >> 3) * PADV + (gg0 & 7) * 8] = vr0;
        *(i32x4*)&Vt[(gg1 >> 3) * PADV + (gg1 & 7) * 8] = vr1;
        __syncthreads();

        // issue next tile's loads NOW — latency hides under this tile's compute
        if (j0 + 1 < jend) {
            const int j1 = j0 + 1;
            kr0 = *(const i32x4*)&kbb[(size_t)j1 * 64 * HD + (size_t)gg0 * 8];
            kr1 = *(const i32x4*)&kbb[(size_t)j1 * 64 * HD + (size_t)gg1 * 8];
            vr0 = *(const i32x4*)&vtbb[(size_t)(gg0 >> 3) * SEQ + j1 * 64 + (gg0 & 7) * 8];
            vr1 = *(const i32x4*)&vtbb[(size_t)(gg1 >> 3) * SEQ + j1 * 64 + (gg1 & 7) * 8];
        }

        // fully-masked tile for this wave? -> skip compute (loads already issued)
        if (j0 * 64 > wtop + 15) continue;

        // ---- S^T = K . Q^T ----
        f32x4 st[4];
        __builtin_amdgcn_s_setprio(1);
#pragma unroll
        for (int mt = 0; mt < 4; ++mt) {
            f32x4 a = (f32x4){0.f, 0.f, 0.f, 0.f};
#pragma unroll
            for (int ks = 0; ks < 4; ++ks) {
                bf16x8 kf = *(const bf16x8*)&Ks[(mt * 16 + l16) * PADK + ks * 32 + quad * 8];
                a = __builtin_amdgcn_mfma_f32_16x16x32_bf16(kf, qf[ks], a, 0, 0, 0);
            }
            st[mt] = a;
        }
        __builtin_amdgcn_s_setprio(0);

        // ---- causal mask (skip when tile fully valid for this wave) ----
        if (j0 * 64 + 63 > wtop) {
#pragma unroll
            for (int mt = 0; mt < 4; ++mt)
#pragma unroll
                for (int rr = 0; rr < 4; ++rr) {
                    int kv = j0 * 64 + mt * 16 + quad * 4 + rr;
                    if (kv > qrow) st[mt][rr] = -1e30f;
                }
        }
        // NOTE: rows with zero valid entries yield m=-1e30 garbage partials;
        // combine neutralizes them via wgt = exp2(-1e30 - M) = 0.

        // ---- online softmax, exp2 domain (lane owns one q-row) ----
        float mx = -1e30f;
#pragma unroll
        for (int mt = 0; mt < 4; ++mt)
#pragma unroll
            for (int rr = 0; rr < 4; ++rr) mx = fmaxf(mx, st[mt][rr]);
        mx = fmaxf(mx, __shfl_xor(mx, 16));
        mx = fmaxf(mx, __shfl_xor(mx, 32));
        // T13 defer-max: only rescale when the wave's max grew past THR
        if (!__all(mx <= m_run + DEFER_THR)) {
            const float m_new = fmaxf(m_run, mx);
            const float alpha = exp2f(m_run - m_new);
            l_run *= alpha;
#pragma unroll
            for (int i = 0; i < 8; ++i) {
                O[i][0] *= alpha; O[i][1] *= alpha; O[i][2] *= alpha; O[i][3] *= alpha;
            }
            m_run = m_new;
        }
        float psum = 0.f;
#pragma unroll
        for (int mt = 0; mt < 4; ++mt)
#pragma unroll
            for (int rr = 0; rr < 4; ++rr) {
                float p = exp2f(st[mt][rr] - m_run);
                st[mt][rr] = p;
                psum += p;
            }
        psum += __shfl_xor(psum, 16);
        psum += __shfl_xor(psum, 32);
        l_run += psum;

        // ---- P^T -> LDS (wave-private rows; no barrier needed) ----
#pragma unroll
        for (int mt = 0; mt < 4; ++mt) {
            short4v p;
            p[0] = (short)f2bf(st[mt][0]); p[1] = (short)f2bf(st[mt][1]);
            p[2] = (short)f2bf(st[mt][2]); p[3] = (short)f2bf(st[mt][3]);
            *(short4v*)&Pt[(w * 16 + l16) * PADP + mt * 16 + quad * 4] = p;
        }

        // ---- O^T += V^T . P^T ----
        bf16x8 pf0 = *(const bf16x8*)&Pt[(w * 16 + l16) * PADP + quad * 8];
        bf16x8 pf1 = *(const bf16x8*)&Pt[(w * 16 + l16) * PADP + 32 + quad * 8];
        __builtin_amdgcn_s_setprio(1);
#pragma unroll
        for (int mt = 0; mt < 8; ++mt) {
            bf16x8 vf0 = *(const bf16x8*)&Vt[(mt * 16 + l16) * PADV + quad * 8];
            bf16x8 vf1 = *(const bf16x8*)&Vt[(mt * 16 + l16) * PADV + 32 + quad * 8];
            O[mt] = __builtin_amdgcn_mfma_f32_16x16x32_bf16(vf0, pf0, O[mt], 0, 0, 0);
            O[mt] = __builtin_amdgcn_mfma_f32_16x16x32_bf16(vf1, pf1, O[mt], 0, 0, 0);
        }
        __builtin_amdgcn_s_setprio(0);
    }

    // ---- partial epilogue: unnormalized O (bf16) + m,l (log2 domain) ----
    const int r = w * 16 + l16;
    const size_t jobbase = (size_t)b * NJOBS + jj;
    unsigned short* po = Opart + jobbase * (128 * 128) + (size_t)r * 128;
#pragma unroll
    for (int mt = 0; mt < 8; ++mt) {
        short4v p;
        p[0] = (short)f2bf(O[mt][0]); p[1] = (short)f2bf(O[mt][1]);
        p[2] = (short)f2bf(O[mt][2]); p[3] = (short)f2bf(O[mt][3]);
        *(short4v*)&po[mt * 16 + quad * 4] = p;
    }
    if (quad == 0) {
        mbuf[jobbase * 128 + r] = m_run;
        lbuf[jobbase * 128 + r] = l_run;
    }
}

// ---------------- Combine partials (log2-domain m) ----------------
// grid (32, 4) x 512 thr: thread -> q-row t>>2 (0..127), 32 head cols at (t&3)*32.
__global__ __launch_bounds__(512) void combine_kernel(
    const unsigned short* __restrict__ Opart, const float* __restrict__ mbuf,
    const float* __restrict__ lbuf, float* __restrict__ out)
{
    const int qi = blockIdx.x, b = blockIdx.y;
    const int nc = (qi + 5) / 5;
    int j0 = 0;
    for (int q = 0; q < qi; ++q) j0 += (q + 5) / 5;
    const int t = threadIdx.x;
    const int row = t >> 2, cg = (t & 3) * 32;

    float mv[MAXC], lv[MAXC];
    float M = -1e30f;
#pragma unroll
    for (int c2 = 0; c2 < MAXC; ++c2) {
        if (c2 < nc) {
            const size_t jb = (size_t)b * NJOBS + j0 + c2;
            mv[c2] = mbuf[jb * 128 + row];
            lv[c2] = lbuf[jb * 128 + row];
            M = fmaxf(M, mv[c2]);
        } else { mv[c2] = -1e30f; lv[c2] = 0.f; }
    }
    float L = 0.f;
#pragma unroll
    for (int c2 = 0; c2 < MAXC; ++c2)
        if (c2 < nc) L += exp2f(mv[c2] - M) * lv[c2];
    const float Linv = 1.0f / L;

    float acc[32];
#pragma unroll
    for (int i = 0; i < 32; ++i) acc[i] = 0.f;
#pragma unroll
    for (int c2 = 0; c2 < MAXC; ++c2) {
        if (c2 < nc) {
            const float wgt = exp2f(mv[c2] - M) * Linv;
            const unsigned short* po = Opart + ((size_t)b * NJOBS + j0 + c2) * (128 * 128) +
                                       (size_t)row * 128 + cg;
#pragma unroll
            for (int i = 0; i < 4; ++i) {
                i32x4 d = *(const i32x4*)&po[i * 8];
#pragma unroll
                for (int e = 0; e < 4; ++e) {
                    unsigned int u = (unsigned int)d[e];
                    acc[i * 8 + e * 2]     = fmaf(wgt, bf2f((unsigned short)(u & 0xffff)), acc[i * 8 + e * 2]);
                    acc[i * 8 + e * 2 + 1] = fmaf(wgt, bf2f((unsigned short)(u >> 16)),   acc[i * 8 + e * 2 + 1]);
                }
            }
        }
    }
    float* op = out + ((size_t)b * SEQ + qi * 128 + row) * HD + cg;
#pragma unroll
    for (int i = 0; i < 8; ++i) {
        float4 res;
        res.x = acc[i * 4]; res.y = acc[i * 4 + 1];
        res.z = acc[i * 4 + 2]; res.w = acc[i * 4 + 3];
        *(float4*)&op[i * 4] = res;
    }
}

extern "C" void kernel_launch(void* const* d_in, const int* in_sizes, int n_in,
                              void* d_out, int out_size, void* d_ws, size_t ws_size,
                              hipStream_t stream) {
    const float* x  = (const float*)d_in[0];
    const float* Wq = (const float*)d_in[1];
    const float* Wk = (const float*)d_in[2];
    const float* Wv = (const float*)d_in[3];

    unsigned short* qb    = (unsigned short*)d_ws;          // [16384][128] bf16
    unsigned short* kb    = qb  + (size_t)MROWS * HD;       // [16384][128] bf16
    unsigned short* vtb   = kb  + (size_t)MROWS * HD;       // [4][128][4096] bf16
    unsigned short* Wt    = vtb + (size_t)MROWS * HD;       // [24][32][64][8] bf16 frag-order
    unsigned short* Opart = Wt  + (size_t)3 * HD * EMB;     // [4][119][128][128] bf16
    float* mbuf = (float*)(Opart + (size_t)BATCH * NJOBS * 128 * 128);
    float* lbuf = mbuf + (size_t)BATCH * NJOBS * 128;
    float* out = (float*)d_out;

    wtrans_kernel <<<dim3(64, 3),  dim3(256), 0, stream>>>(Wq, Wk, Wv, Wt);
    qkv_kernel    <<<dim3(256),    dim3(512), 0, stream>>>(x, Wt, qb, kb, vtb);
    flash_kernel  <<<dim3(480),    dim3(512), 0, stream>>>(qb, kb, vtb, Opart, mbuf, lbuf);
    combine_kernel<<<dim3(32, 4),  dim3(512), 0, stream>>>(Opart, mbuf, lbuf, out);
}

// Round 5
// 169.011 us; speedup vs baseline: 1.1277x; 1.0149x over previous
//
#include <hip/hip_runtime.h>
#include <math.h>

#define BATCH 4
#define SEQ   4096
#define EMB   1024
#define HD    128
#define MROWS (BATCH*SEQ)
#define SCALE  0.08838834764831844f   // 1/sqrt(128)
#define SCALEQ 0.12751742f            // (1/sqrt(128)) * log2(e)  -> exp2-domain scores
#define CHUNK 10                      // kv-tiles (of 64) per split-KV job
#define NJOBS 119                     // jobs per batch at BQ=128, CHUNK=10
#define MAXC  7                       // max chunks per q-tile = ceil(64/10)

typedef __attribute__((ext_vector_type(8))) short bf16x8;   // MFMA A/B frag (4 VGPR)
typedef __attribute__((ext_vector_type(4))) short short4v;  // 8B LDS store
typedef __attribute__((ext_vector_type(4))) float f32x4;    // MFMA C/D frag
typedef __attribute__((ext_vector_type(4))) int   i32x4;    // 16B copy
typedef __attribute__((ext_vector_type(2))) int   i32x2;    // 8B copy

static __device__ __forceinline__ unsigned short f2bf(float f) {
    unsigned int u = __float_as_uint(f);
    u += 0x7fff + ((u >> 16) & 1);       // RNE
    return (unsigned short)(u >> 16);
}
static __device__ __forceinline__ float bf2f(unsigned short s) {
    return __uint_as_float((unsigned int)s << 16);
}
static __device__ __forceinline__ short4v pack4(float4 a) {
    short4v p;
    p[0] = (short)f2bf(a.x); p[1] = (short)f2bf(a.y);
    p[2] = (short)f2bf(a.z); p[3] = (short)f2bf(a.w);
    return p;
}
// HW packed f32->bf16 RNE: replaces 8 VALU ops (2x manual f2bf) with 1
static __device__ __forceinline__ int cvtpk(float lo, float hi) {
    int r;
    asm("v_cvt_pk_bf16_f32 %0, %1, %2" : "=v"(r) : "v"(lo), "v"(hi));
    return r;
}
// async global->LDS, 16B/lane: dest = wave-uniform base + lane*16 (linear)
static __device__ __forceinline__ void gload_lds16(const unsigned short* g, unsigned short* l) {
    __builtin_amdgcn_global_load_lds(
        (const __attribute__((address_space(1))) void*)g,
        (__attribute__((address_space(3))) void*)l, 16, 0, 0);
}

// ---------------- W transpose + bf16 -> FRAGMENT-CONTIGUOUS layout ----------------
// Wfrag[ntg][kc][lane] of 16B, ntg = (w*128+n)>>4 (24 tiles), kc = k>>5 (32 chunks),
// lane = quad*16 + (n&15), quad = (k>>3)&3, element e = k&7.
// A wave's MFMA B-frag for (ntg,kc) is ONE contiguous 1KB block.
__global__ __launch_bounds__(256) void wtrans_kernel(
    const float* __restrict__ Wq, const float* __restrict__ Wk,
    const float* __restrict__ Wv, unsigned short* __restrict__ Wt)
{
    __shared__ __align__(16) unsigned short Xs[16 * 132];
    const int w  = blockIdx.y;
    const float* W = (w == 0) ? Wq : (w == 1) ? Wk : Wv;
    const float sc = (w == 0) ? SCALEQ : 1.0f;   // exp2-domain: scores carry log2(e)
    const int bx = blockIdx.x;
    const int k0 = bx * 16;
    const int t  = threadIdx.x;

#pragma unroll
    for (int i = 0; i < 2; ++i) {
        int gg = i * 256 + t;                 // 0..511
        int row = gg >> 5, c4 = gg & 31;      // row = k-row in tile, c4*4 = n
        float4 a = *(const float4*)&W[(size_t)(k0 + row) * HD + c4 * 4];
        short4v p;
        p[0] = (short)f2bf(a.x * sc); p[1] = (short)f2bf(a.y * sc);
        p[2] = (short)f2bf(a.z * sc); p[3] = (short)f2bf(a.w * sc);
        *(short4v*)&Xs[row * 132 + c4 * 4] = p;
    }
    __syncthreads();
    // thread -> (n, g): 8 consecutive k = k0 + g*8 + 0..7 of column n
    const int n = t >> 1, g = t & 1;
    i32x4 o;
#pragma unroll
    for (int e = 0; e < 4; ++e) {
        unsigned int lo = Xs[(g * 8 + e * 2    ) * 132 + n];
        unsigned int hi = Xs[(g * 8 + e * 2 + 1) * 132 + n];
        o[e] = (int)(lo | (hi << 16));
    }
    const int ntg  = w * 8 + (n >> 4);
    const int kc   = bx >> 1;
    const int quad = (bx * 2 + g) & 3;
    const int lane = quad * 16 + (n & 15);
    *(i32x4*)&Wt[(((size_t)ntg * 32 + kc) * 64 + lane) * 8] = o;
}

// ---------------- Fused QKV: global_load_lds W dbuf + write-late x, 1 barrier/phase ----------------
// grid 256 x 512 thr (8 waves), 1 block/CU (114KB LDS). Wave ng owns ntg 3ng..3ng+2.
// Per phase (64 K-elems): stage next W via 6x global_load_lds (wave-private, linear,
// 1KB each) -> ds_write x(next) from regs loaded 2 phases ago -> issue x(ph+2) ->
// 14x ds_read_b128 + 24 MFMA -> counted s_waitcnt vmcnt(2) (drains 6 W gloads,
// leaves 2 x loads in flight) -> lgkmcnt(0) -> barrier. Tail phases use clamped
// indices (junk loads to dead buffers) so the vmcnt invariant is uniform.
// Round 1-4 lesson: reg-prefetched W across barriers is compiler-fragile;
// global_load_lds + counted vmcnt is the proven plain-HIP mechanism (T3/T4).
__global__ __launch_bounds__(512, 2) void qkv_kernel(
    const float* __restrict__ x, const unsigned short* __restrict__ Wt,
    unsigned short* __restrict__ qb, unsigned short* __restrict__ kb,
    unsigned short* __restrict__ vtb)
{
    __shared__ __align__(1024) unsigned short lds[58368];  // W dbuf 96KB + x dbuf 18.4KB
    unsigned short* Ws  = lds;           // [2][24][2][512] shorts (buf, ntg, kcl, 1KB frag)
    unsigned short* xsA = lds + 49152;   // x tile 64 x 64, pad 72 (buf 0)
    unsigned short* xsB = lds + 53760;   // buf 1

    const int t    = threadIdx.x;
    const int lane = t & 63, ng = t >> 6;
    const int quad = lane >> 4, l16 = lane & 15;
    const int m0   = blockIdx.x * 64;

    f32x4 acc[4][3];
#pragma unroll
    for (int i = 0; i < 4; ++i)
#pragma unroll
        for (int j = 0; j < 3; ++j) acc[i][j] = (f32x4){0.f, 0.f, 0.f, 0.f};

    // x staging: 64 rows x 64 floats/phase = 1024 float4; thread covers idx t, t+512
    const int xr0 = t >> 4,         xc0 = (t & 15) * 4;
    const int xr1 = (t + 512) >> 4, xc1 = ((t + 512) & 15) * 4;
    const float* xb0 = x + (size_t)(m0 + xr0) * EMB + xc0;
    const float* xb1 = x + (size_t)(m0 + xr1) * EMB + xc1;

    // W: per-lane 16B slot in the frag-contiguous layout
    const unsigned short* Wg = Wt + (size_t)lane * 8;
    float4 xra, xrb;

    // ---- prologue: stage x(ph0) directly; stage W(ph0)->buf0; issue x(ph1) regs ----
    {
        float4 a = *(const float4*)&xb0[0];
        float4 b = *(const float4*)&xb1[0];
        *(short4v*)&xsA[xr0 * 72 + xc0] = pack4(a);
        *(short4v*)&xsA[xr1 * 72 + xc1] = pack4(b);
#pragma unroll
        for (int jt = 0; jt < 3; ++jt)
#pragma unroll
            for (int kcl = 0; kcl < 2; ++kcl) {
                int ntg = ng * 3 + jt;
                gload_lds16(Wg + ((size_t)ntg * 32 + kcl) * 512,
                            Ws + ((size_t)ntg * 2 + kcl) * 512);
            }
        xra = *(const float4*)&xb0[64];
        xrb = *(const float4*)&xb1[64];
    }
    asm volatile("s_waitcnt vmcnt(2)" ::: "memory");   // drain W gloads; x regs in flight
    asm volatile("s_waitcnt lgkmcnt(0)" ::: "memory");
    __builtin_amdgcn_s_barrier();

    for (int ph = 0; ph < 16; ++ph) {
        const int cb = ph & 1, nb = cb ^ 1;
        unsigned short* xc = cb ? xsB : xsA;
        unsigned short* xn = cb ? xsA : xsB;
        const int kcn = (ph < 15 ? ph + 1 : 15) * 2;      // clamped next-phase kc base

        // (1) stage next W -> buf nb (6 gloads, wave-private)
#pragma unroll
        for (int jt = 0; jt < 3; ++jt)
#pragma unroll
            for (int kcl = 0; kcl < 2; ++kcl) {
                int ntg = ng * 3 + jt;
                gload_lds16(Wg + ((size_t)ntg * 32 + kcn + kcl) * 512,
                            Ws + ((size_t)(nb * 48) + ntg * 2 + kcl) * 512);
            }
        // (2) write-late x staging (xra/xrb issued one phase ago)
        *(short4v*)&xn[xr0 * 72 + xc0] = pack4(xra);
        *(short4v*)&xn[xr1 * 72 + xc1] = pack4(xrb);
        // (3) issue x(ph+2) loads (clamped in tail; junk lands in dead buffer)
        {
            const int xcol = (ph + 2 < 16) ? (ph + 2) * 64 : 960;
            xra = *(const float4*)&xb0[xcol];
            xrb = *(const float4*)&xb1[xcol];
        }
        // (4) compute from buf cb
        {
            bf16x8 aA[2][4], aB[2][3];
#pragma unroll
            for (int ks = 0; ks < 2; ++ks)
#pragma unroll
                for (int jt = 0; jt < 3; ++jt)
                    aB[ks][jt] = *(const bf16x8*)&Ws[((size_t)(cb * 48) + (ng * 3 + jt) * 2 + ks) * 512 + lane * 8];
#pragma unroll
            for (int ks = 0; ks < 2; ++ks)
#pragma unroll
                for (int mt = 0; mt < 4; ++mt)
                    aA[ks][mt] = *(const bf16x8*)&xc[(mt * 16 + l16) * 72 + ks * 32 + quad * 8];
            __builtin_amdgcn_s_setprio(1);
#pragma unroll
            for (int ks = 0; ks < 2; ++ks)
#pragma unroll
                for (int mt = 0; mt < 4; ++mt)
#pragma unroll
                    for (int jt = 0; jt < 3; ++jt)
                        acc[mt][jt] = __builtin_amdgcn_mfma_f32_16x16x32_bf16(
                            aA[ks][mt], aB[ks][jt], acc[mt][jt], 0, 0, 0);
            __builtin_amdgcn_s_setprio(0);
        }
        // (5) counted drain: 6 W gloads done, 2 x loads stay in flight
        asm volatile("s_waitcnt vmcnt(2)" ::: "memory");
        asm volatile("s_waitcnt lgkmcnt(0)" ::: "memory");
        __builtin_amdgcn_s_barrier();
    }

    // ---- epilogue: scatter to LDS (per-matrix layout), then coalesced copy out ----
    unsigned short* Cq = lds;                 // [64][136]
    unsigned short* Ck = lds + 64 * 136;      // [64][136]
    unsigned short* Cv = lds + 2 * 64 * 136;  // [128][72] transposed
#pragma unroll
    for (int mt = 0; mt < 4; ++mt)
#pragma unroll
        for (int jt = 0; jt < 3; ++jt) {
            int nt = ng * 3 + jt;
            int wm = nt >> 3, nl = nt & 7;
            if (wm < 2) {
                unsigned short* C = (wm == 0) ? Cq : Ck;
#pragma unroll
                for (int rr = 0; rr < 4; ++rr)
                    C[(mt * 16 + quad * 4 + rr) * 136 + nl * 16 + l16] =
                        f2bf(acc[mt][jt][rr]);
            } else {
                i32x2 p;
                p[0] = cvtpk(acc[mt][jt][0], acc[mt][jt][1]);
                p[1] = cvtpk(acc[mt][jt][2], acc[mt][jt][3]);
                *(i32x2*)&Cv[(nl * 16 + l16) * 72 + mt * 16 + quad * 4] = p;
            }
        }
    __syncthreads();
    {   // q, k: 64 x 128 each -> 1024 i32x4; thread handles idx t, t+512
#pragma unroll
        for (int i = 0; i < 2; ++i) {
            int idx = i * 512 + t;
            int row = idx >> 4, seg = idx & 15;
            *(i32x4*)&qb[((size_t)(m0 + row)) * HD + seg * 8] = *(const i32x4*)&Cq[row * 136 + seg * 8];
            *(i32x4*)&kb[((size_t)(m0 + row)) * HD + seg * 8] = *(const i32x4*)&Ck[row * 136 + seg * 8];
        }
    }
    {   // v^T: 128 x 64 -> 1024 i32x4; thread handles idx t, t+512
        const int b = m0 >> 12, s0 = m0 & 4095;
#pragma unroll
        for (int i = 0; i < 2; ++i) {
            int idx = i * 512 + t;
            int h = idx >> 3, seg = idx & 7;
            *(i32x4*)&vtb[(size_t)b * (HD * SEQ) + (size_t)h * SEQ + s0 + seg * 8] =
                *(const i32x4*)&Cv[h * 72 + seg * 8];
        }
    }
}

// ---------------- Flash attention: split-KV, BQ=128, 8 waves, XCD-batch affinity ----------------
// grid 480 x 512 thr. T14 async-stage K/V; exp2-domain softmax + T13 defer-max;
// v_cvt_pk_bf16_f32 for all f32->bf16 packs (was 4 VALU/value manual RNE).
#define PADK 136
#define PADV 72
#define PADP 72
#define DEFER_THR 8.0f   // log2 domain: P bounded by 2^8=256, safe in bf16/f32

__global__ __launch_bounds__(512, 4) void flash_kernel(
    const unsigned short* __restrict__ qb, const unsigned short* __restrict__ kb,
    const unsigned short* __restrict__ vtb, unsigned short* __restrict__ Opart,
    float* __restrict__ mbuf, float* __restrict__ lbuf)
{
    __shared__ __align__(16) unsigned short Ks[64 * PADK];    // 17.4 KB
    __shared__ __align__(16) unsigned short Vt[128 * PADV];   // 18.4 KB
    __shared__ __align__(16) unsigned short Pt[128 * PADP];   // 18.4 KB

    const int bx   = blockIdx.x;
    const int slot = bx & 7, pp = bx >> 3;
    const int b    = slot >> 1;
    const int jj   = pp * 2 + (slot & 1);
    if (jj >= NJOBS) return;                 // dummy pad blocks (no barrier yet)

    const int t    = threadIdx.x;
    const int lane = t & 63, w = t >> 6;     // 8 waves
    const int quad = lane >> 4, l16 = lane & 15;

    // decode jj -> (qi, c): q-tile qi has ceil((qi+1)/5) chunks
    int qi = 0, s = 0;
    for (qi = 0; qi < 32; ++qi) {
        int cnt = (qi + 5) / 5;
        if (jj < s + cnt) break;
        s += cnt;
    }
    const int c    = jj - s;
    const int qrow = qi * 128 + w * 16 + l16;
    const int jmax = 2 * qi + 2;
    const int jbeg = c * CHUNK;
    const int jend = min(jbeg + CHUNK, jmax);
    const int wtop = qi * 128 + w * 16;      // wave's lowest q-row

    bf16x8 qf[4];
    {
        const unsigned short* qp = qb + ((size_t)b * SEQ + qrow) * HD;
#pragma unroll
        for (int ks = 0; ks < 4; ++ks)
            qf[ks] = *(const bf16x8*)&qp[ks * 32 + quad * 8];
    }

    f32x4 O[8];
#pragma unroll
    for (int i = 0; i < 8; ++i) O[i] = (f32x4){0.f, 0.f, 0.f, 0.f};
    float m_run = -1e30f, l_run = 0.f;

    const unsigned short* kbb  = kb  + (size_t)b * SEQ * HD;
    const unsigned short* vtbb = vtb + (size_t)b * HD * SEQ;

    const int gg0 = t, gg1 = 512 + t;
    // prologue: load first tile into regs
    i32x4 kr0, kr1, vr0, vr1;
    kr0 = *(const i32x4*)&kbb[(size_t)jbeg * 64 * HD + (size_t)gg0 * 8];
    kr1 = *(const i32x4*)&kbb[(size_t)jbeg * 64 * HD + (size_t)gg1 * 8];
    vr0 = *(const i32x4*)&vtbb[(size_t)(gg0 >> 3) * SEQ + jbeg * 64 + (gg0 & 7) * 8];
    vr1 = *(const i32x4*)&vtbb[(size_t)(gg1 >> 3) * SEQ + jbeg * 64 + (gg1 & 7) * 8];

    for (int j0 = jbeg; j0 < jend; ++j0) {
        __syncthreads();   // prior iteration's reads of Ks/Vt complete (WAR)
        // write prefetched tile (vmcnt drained here, hidden under prior compute)
        *(i32x4*)&Ks[(gg0 >> 4) * PADK + (gg0 & 15) * 8] = kr0;
        *(i32x4*)&Ks[(gg1 >> 4) * PADK + (gg1 & 15) * 8] = kr1;
        *(i32x4*)&Vt[(gg0 >> 3) * PADV + (gg0 & 7) * 8] = vr0;
        *(i32x4*)&Vt[(gg1 >> 3) * PADV + (gg1 & 7) * 8] = vr1;
        __syncthreads();

        // issue next tile's loads NOW — latency hides under this tile's compute
        if (j0 + 1 < jend) {
            const int j1 = j0 + 1;
            kr0 = *(const i32x4*)&kbb[(size_t)j1 * 64 * HD + (size_t)gg0 * 8];
            kr1 = *(const i32x4*)&kbb[(size_t)j1 * 64 * HD + (size_t)gg1 * 8];
            vr0 = *(const i32x4*)&vtbb[(size_t)(gg0 >> 3) * SEQ + j1 * 64 + (gg0 & 7) * 8];
            vr1 = *(const i32x4*)&vtbb[(size_t)(gg1 >> 3) * SEQ + j1 * 64 + (gg1 & 7) * 8];
        }

        // fully-masked tile for this wave? -> skip compute (loads already issued)
        if (j0 * 64 > wtop + 15) continue;

        // ---- S^T = K . Q^T ----
        f32x4 st[4];
        __builtin_amdgcn_s_setprio(1);
#pragma unroll
        for (int mt = 0; mt < 4; ++mt) {
            f32x4 a = (f32x4){0.f, 0.f, 0.f, 0.f};
#pragma unroll
            for (int ks = 0; ks < 4; ++ks) {
                bf16x8 kf = *(const bf16x8*)&Ks[(mt * 16 + l16) * PADK + ks * 32 + quad * 8];
                a = __builtin_amdgcn_mfma_f32_16x16x32_bf16(kf, qf[ks], a, 0, 0, 0);
            }
            st[mt] = a;
        }
        __builtin_amdgcn_s_setprio(0);

        // ---- causal mask (skip when tile fully valid for this wave) ----
        if (j0 * 64 + 63 > wtop) {
#pragma unroll
            for (int mt = 0; mt < 4; ++mt)
#pragma unroll
                for (int rr = 0; rr < 4; ++rr) {
                    int kv = j0 * 64 + mt * 16 + quad * 4 + rr;
                    if (kv > qrow) st[mt][rr] = -1e30f;
                }
        }
        // NOTE: rows with zero valid entries yield m=-1e30 garbage partials;
        // combine neutralizes them via wgt = exp2(-1e30 - M) = 0.

        // ---- online softmax, exp2 domain (lane owns one q-row) ----
        float mx = -1e30f;
#pragma unroll
        for (int mt = 0; mt < 4; ++mt)
#pragma unroll
            for (int rr = 0; rr < 4; ++rr) mx = fmaxf(mx, st[mt][rr]);
        mx = fmaxf(mx, __shfl_xor(mx, 16));
        mx = fmaxf(mx, __shfl_xor(mx, 32));
        // T13 defer-max: only rescale when the wave's max grew past THR
        if (!__all(mx <= m_run + DEFER_THR)) {
            const float m_new = fmaxf(m_run, mx);
            const float alpha = exp2f(m_run - m_new);
            l_run *= alpha;
#pragma unroll
            for (int i = 0; i < 8; ++i) {
                O[i][0] *= alpha; O[i][1] *= alpha; O[i][2] *= alpha; O[i][3] *= alpha;
            }
            m_run = m_new;
        }
        float psum = 0.f;
#pragma unroll
        for (int mt = 0; mt < 4; ++mt)
#pragma unroll
            for (int rr = 0; rr < 4; ++rr) {
                float p = exp2f(st[mt][rr] - m_run);
                st[mt][rr] = p;
                psum += p;
            }
        psum += __shfl_xor(psum, 16);
        psum += __shfl_xor(psum, 32);
        l_run += psum;

        // ---- P^T -> LDS via cvt_pk (wave-private rows; no barrier needed) ----
#pragma unroll
        for (int mt = 0; mt < 4; ++mt) {
            i32x2 p;
            p[0] = cvtpk(st[mt][0], st[mt][1]);
            p[1] = cvtpk(st[mt][2], st[mt][3]);
            *(i32x2*)&Pt[(w * 16 + l16) * PADP + mt * 16 + quad * 4] = p;
        }

        // ---- O^T += V^T . P^T ----
        bf16x8 pf0 = *(const bf16x8*)&Pt[(w * 16 + l16) * PADP + quad * 8];
        bf16x8 pf1 = *(const bf16x8*)&Pt[(w * 16 + l16) * PADP + 32 + quad * 8];
        __builtin_amdgcn_s_setprio(1);
#pragma unroll
        for (int mt = 0; mt < 8; ++mt) {
            bf16x8 vf0 = *(const bf16x8*)&Vt[(mt * 16 + l16) * PADV + quad * 8];
            bf16x8 vf1 = *(const bf16x8*)&Vt[(mt * 16 + l16) * PADV + 32 + quad * 8];
            O[mt] = __builtin_amdgcn_mfma_f32_16x16x32_bf16(vf0, pf0, O[mt], 0, 0, 0);
            O[mt] = __builtin_amdgcn_mfma_f32_16x16x32_bf16(vf1, pf1, O[mt], 0, 0, 0);
        }
        __builtin_amdgcn_s_setprio(0);
    }

    // ---- partial epilogue: unnormalized O (bf16, cvt_pk) + m,l (log2 domain) ----
    const int r = w * 16 + l16;
    const size_t jobbase = (size_t)b * NJOBS + jj;
    unsigned short* po = Opart + jobbase * (128 * 128) + (size_t)r * 128;
#pragma unroll
    for (int mt = 0; mt < 8; ++mt) {
        i32x2 p;
        p[0] = cvtpk(O[mt][0], O[mt][1]);
        p[1] = cvtpk(O[mt][2], O[mt][3]);
        *(i32x2*)&po[mt * 16 + quad * 4] = p;
    }
    if (quad == 0) {
        mbuf[jobbase * 128 + r] = m_run;
        lbuf[jobbase * 128 + r] = l_run;
    }
}

// ---------------- Combine partials (log2-domain m) ----------------
// grid (32, 4) x 512 thr: thread -> q-row t>>2 (0..127), 32 head cols at (t&3)*32.
__global__ __launch_bounds__(512) void combine_kernel(
    const unsigned short* __restrict__ Opart, const float* __restrict__ mbuf,
    const float* __restrict__ lbuf, float* __restrict__ out)
{
    const int qi = blockIdx.x, b = blockIdx.y;
    const int nc = (qi + 5) / 5;
    int j0 = 0;
    for (int q = 0; q < qi; ++q) j0 += (q + 5) / 5;
    const int t = threadIdx.x;
    const int row = t >> 2, cg = (t & 3) * 32;

    float mv[MAXC], lv[MAXC];
    float M = -1e30f;
#pragma unroll
    for (int c2 = 0; c2 < MAXC; ++c2) {
        if (c2 < nc) {
            const size_t jb = (size_t)b * NJOBS + j0 + c2;
            mv[c2] = mbuf[jb * 128 + row];
            lv[c2] = lbuf[jb * 128 + row];
            M = fmaxf(M, mv[c2]);
        } else { mv[c2] = -1e30f; lv[c2] = 0.f; }
    }
    float L = 0.f;
#pragma unroll
    for (int c2 = 0; c2 < MAXC; ++c2)
        if (c2 < nc) L += exp2f(mv[c2] - M) * lv[c2];
    const float Linv = 1.0f / L;

    float acc[32];
#pragma unroll
    for (int i = 0; i < 32; ++i) acc[i] = 0.f;
#pragma unroll
    for (int c2 = 0; c2 < MAXC; ++c2) {
        if (c2 < nc) {
            const float wgt = exp2f(mv[c2] - M) * Linv;
            const unsigned short* po = Opart + ((size_t)b * NJOBS + j0 + c2) * (128 * 128) +
                                       (size_t)row * 128 + cg;
#pragma unroll
            for (int i = 0; i < 4; ++i) {
                i32x4 d = *(const i32x4*)&po[i * 8];
#pragma unroll
                for (int e = 0; e < 4; ++e) {
                    unsigned int u = (unsigned int)d[e];
                    acc[i * 8 + e * 2]     = fmaf(wgt, bf2f((unsigned short)(u & 0xffff)), acc[i * 8 + e * 2]);
                    acc[i * 8 + e * 2 + 1] = fmaf(wgt, bf2f((unsigned short)(u >> 16)),   acc[i * 8 + e * 2 + 1]);
                }
            }
        }
    }
    float* op = out + ((size_t)b * SEQ + qi * 128 + row) * HD + cg;
#pragma unroll
    for (int i = 0; i < 8; ++i) {
        float4 res;
        res.x = acc[i * 4]; res.y = acc[i * 4 + 1];
        res.z = acc[i * 4 + 2]; res.w = acc[i * 4 + 3];
        *(float4*)&op[i * 4] = res;
    }
}

extern "C" void kernel_launch(void* const* d_in, const int* in_sizes, int n_in,
                              void* d_out, int out_size, void* d_ws, size_t ws_size,
                              hipStream_t stream) {
    const float* x  = (const float*)d_in[0];
    const float* Wq = (const float*)d_in[1];
    const float* Wk = (const float*)d_in[2];
    const float* Wv = (const float*)d_in[3];

    unsigned short* qb    = (unsigned short*)d_ws;          // [16384][128] bf16
    unsigned short* kb    = qb  + (size_t)MROWS * HD;       // [16384][128] bf16
    unsigned short* vtb   = kb  + (size_t)MROWS * HD;       // [4][128][4096] bf16
    unsigned short* Wt    = vtb + (size_t)MROWS * HD;       // [24][32][64][8] bf16 frag-order
    unsigned short* Opart = Wt  + (size_t)3 * HD * EMB;     // [4][119][128][128] bf16
    float* mbuf = (float*)(Opart + (size_t)BATCH * NJOBS * 128 * 128);
    float* lbuf = mbuf + (size_t)BATCH * NJOBS * 128;
    float* out = (float*)d_out;

    wtrans_kernel <<<dim3(64, 3),  dim3(256), 0, stream>>>(Wq, Wk, Wv, Wt);
    qkv_kernel    <<<dim3(256),    dim3(512), 0, stream>>>(x, Wt, qb, kb, vtb);
    flash_kernel  <<<dim3(480),    dim3(512), 0, stream>>>(qb, kb, vtb, Opart, mbuf, lbuf);
    combine_kernel<<<dim3(32, 4),  dim3(512), 0, stream>>>(Opart, mbuf, lbuf, out);
}